// Round 11
// baseline (1741.836 us; speedup 1.0000x reference)
//
#include <hip/hip_runtime.h>
#include <hip/hip_bf16.h>
#include <math.h>

// Problem constants (from reference)
#define BGRAPH 8192
#define NPG 32
#define EPG 64
#define NNODE (BGRAPH * NPG)   // 262144
#define NEDGE (BGRAPH * EPG)   // 524288
#define CELLD 908
#define BN_EPS 1e-5f

typedef __attribute__((ext_vector_type(8))) short bf16x8;   // 8 bf16 = 4 VGPRs
typedef __attribute__((ext_vector_type(4))) float f32x4;
typedef __attribute__((ext_vector_type(4))) unsigned short us4;

__device__ __forceinline__ unsigned short f2bf(float f)
{
    unsigned int u = __float_as_uint(f);
    u = (u + 0x7FFFu + ((u >> 16) & 1u)) >> 16;   // RNE
    return (unsigned short)u;
}

__device__ __forceinline__ bf16x8 quant8(const float v[8])
{
    union { bf16x8 b; unsigned short u[8]; } fr;
    #pragma unroll
    for (int j = 0; j < 8; ++j) fr.u[j] = f2bf(v[j]);
    return fr.b;
}

__device__ __forceinline__ void bf2f8(bf16x8 b, float v[8])
{
    union { bf16x8 bb; unsigned short u[8]; } x; x.bb = b;
    #pragma unroll
    for (int j = 0; j < 8; ++j) v[j] = __uint_as_float((unsigned)x.u[j] << 16);
}

// in_mode: 0=raw, 1=relu((x-m)*iv), 2=elu((x-m)*iv), 3=(relu(x)-m)*iv
__device__ __forceinline__ float apply_in(float v, int mode, float mn, float iv)
{
    if (mode == 1)      { v = (v - mn) * iv; v = fmaxf(v, 0.f); }
    else if (mode == 2) { v = (v - mn) * iv; v = (v > 0.f) ? v : expm1f(v); }
    else if (mode == 3) { v = fmaxf(v, 0.f); v = (v - mn) * iv; }
    return v;
}

// ---------------------------------------------------------------------------
// Merged setup: weight transpose+bf16, stats zero, per-graph in-edge CSR.
// ---------------------------------------------------------------------------
struct TSeg { const float* w; unsigned short* wt; int K; int N; int off; };
struct SetupArgs {
    TSeg s[11]; int tTotal; int tBlocks;
    float* zb; int zTotal; int zBlocks;
    const int* src; const int* dst; int* row_start; int* col_idx;
};

__global__ void setup_all(SetupArgs a)
{
    int b = blockIdx.x;
    int tid = threadIdx.x;
    if (b < a.tBlocks) {
        int i = b * 256 + tid;
        if (i < a.tTotal) {
            int j = 0;
            while (j < 10 && i >= a.s[j + 1].off) ++j;
            int idx = i - a.s[j].off;
            int K = a.s[j].K, N = a.s[j].N;
            int n = idx / K, k = idx - n * K;
            a.s[j].wt[idx] = f2bf(a.s[j].w[(size_t)k * N + n]);
        }
        return;
    }
    b -= a.tBlocks;
    if (b < a.zBlocks) {
        int i = b * 256 + tid;
        if (i < a.zTotal) a.zb[i] = 0.f;
        return;
    }
    b -= a.zBlocks;
    // CSR build: 4 graphs per block
    __shared__ int cnt[4][32], fill[4][32], rsl[4][33];
    int gl = tid >> 6, e = tid & 63;
    int g = b * 4 + gl;
    if (e < 32) { cnt[gl][e] = 0; fill[gl][e] = 0; }
    __syncthreads();
    int s = a.src[g * EPG + e] - g * NPG;
    int d = a.dst[g * EPG + e] - g * NPG;
    atomicAdd(&cnt[gl][d], 1);
    __syncthreads();
    if (e == 0) {
        int acc = 0;
        for (int i = 0; i < 32; ++i) { rsl[gl][i] = acc; acc += cnt[gl][i]; }
        rsl[gl][32] = acc;
    }
    __syncthreads();
    int pos = rsl[gl][d] + atomicAdd(&fill[gl][d], 1);
    a.col_idx[g * EPG + pos] = s;
    if (e < 33) a.row_start[g * 33 + e] = rsl[gl][e];
}

// ---------------------------------------------------------------------------
// GIN chain by RECOMPUTE, BARRIER-FREE: block = 4 graphs, wave = 1 graph.
// All LDS state is per-wave (w11l duplicate-written with identical values by
// every wave), so NO __syncthreads anywhere. h tile stored bf16 (40.5 KB LDS
// -> 4 blocks/CU = 16 waves). Stats via per-wave shuffle + direct atomics.
// Chain: a = x + agg(x); u1 = a@W11+b11 [stats raw @D1]
//        u2 = relu(bn(u1))@W12+b12     [stats relu @D2]
//        h  = bn(relu(u2)); u3 = (h+agg(h))@W21+b21 [stats raw @D3]
//        u4 = relu(bn(u3))@W22+b22     [stats relu + pool @D4]
// ---------------------------------------------------------------------------
#define HBS 136   // bf16 h row stride (ushorts): 272 B, 16B-aligned

template<int DEPTH>
__launch_bounds__(256)
__global__ void gin_chain(const float* __restrict__ drug_x,
                          const int* __restrict__ row_start,
                          const int* __restrict__ col_idx,
                          const unsigned short* __restrict__ W11,   // [128][9]
                          const float* __restrict__ b11,
                          const unsigned short* __restrict__ W12, const float* __restrict__ b12,
                          const unsigned short* __restrict__ W21, const float* __restrict__ b21,
                          const unsigned short* __restrict__ W22, const float* __restrict__ b22,
                          const float* __restrict__ st1,
                          const float* __restrict__ st2,
                          const float* __restrict__ st3,
                          float invM,
                          float* __restrict__ out_stats,
                          float* __restrict__ pool_out)
{
    __shared__ __align__(16) unsigned short h[4 * 32 * HBS];    // 34816 B
    __shared__ __align__(16) unsigned short w11l[128 * 16];     // 4096 B (dup-written)
    __shared__ int rs[4][36];                                   // 576 B
    __shared__ int ci[4][64];                                   // 1024 B

    int tid  = threadIdx.x;
    int wave = tid >> 6;
    int lane = tid & 63;
    int quad = lane >> 4;
    int l16  = lane & 15;
    int g0   = blockIdx.x * 4;
    unsigned short* hw = h + wave * (32 * HBS);
    float* xw = (float*)hw;          // stage-1 fp32 x tile (32x16), overlaid

    // ---- per-wave staging (no cross-wave deps -> no barriers) ----
    for (int i = lane; i < 128 * 16; i += 64) {
        int n = i >> 4, k = i & 15;
        w11l[i] = (k < 9) ? W11[n * 9 + k] : (unsigned short)0;
    }
    if (lane <= 32) rs[wave][lane] = row_start[(g0 + wave) * 33 + lane];
    ci[wave][lane] = col_idx[(g0 + wave) * EPG + lane];
    {
        const float* xg = drug_x + (size_t)(g0 + wave) * 32 * 9;
        for (int i = lane; i < 32 * 16; i += 64) {
            int rr = i >> 4, c = i & 15;
            xw[i] = (c < 9) ? xg[rr * 9 + c] : 0.f;
        }
    }

    f32x4 acc[2][8];
    #pragma unroll
    for (int i = 0; i < 2; ++i)
        #pragma unroll
        for (int j = 0; j < 8; ++j)
            acc[i][j] = (f32x4){0.f, 0.f, 0.f, 0.f};

    // ======== stage 1: u1 = (x + agg(x)) @ W11 + b11 (fp32 gather) ==========
    {
        bf16x8 af[2];
        #pragma unroll
        for (int mt = 0; mt < 2; ++mt) {
            int rowl = mt * 16 + l16;
            float v[8] = {0, 0, 0, 0, 0, 0, 0, 0};
            if (quad < 2) {
                float4 lo = *(const float4*)&xw[rowl * 16 + quad * 8];
                float4 hi = *(const float4*)&xw[rowl * 16 + quad * 8 + 4];
                v[0] = lo.x; v[1] = lo.y; v[2] = lo.z; v[3] = lo.w;
                v[4] = hi.x; v[5] = hi.y; v[6] = hi.z; v[7] = hi.w;
                int e0 = rs[wave][rowl], e1 = rs[wave][rowl + 1];
                for (int e = e0; e < e1; ++e) {
                    int sr = ci[wave][e];
                    float4 l2 = *(const float4*)&xw[sr * 16 + quad * 8];
                    float4 h2 = *(const float4*)&xw[sr * 16 + quad * 8 + 4];
                    v[0] += l2.x; v[1] += l2.y; v[2] += l2.z; v[3] += l2.w;
                    v[4] += h2.x; v[5] += h2.y; v[6] += h2.z; v[7] += h2.w;
                }
            }
            af[mt] = quant8(v);
        }
        #pragma unroll
        for (int nt = 0; nt < 8; ++nt) {
            bf16x8 b;
            if (quad < 2) b = *(const bf16x8*)(const void*)&w11l[(nt * 16 + l16) * 16 + quad * 8];
            else { float z[8] = {0,0,0,0,0,0,0,0}; b = quant8(z); }
            acc[0][nt] = __builtin_amdgcn_mfma_f32_16x16x32_bf16(af[0], b, acc[0][nt], 0, 0, 0);
            acc[1][nt] = __builtin_amdgcn_mfma_f32_16x16x32_bf16(af[1], b, acc[1][nt], 0, 0, 0);
        }
        #pragma unroll
        for (int nt = 0; nt < 8; ++nt) {
            float bv = b11[nt * 16 + l16];
            #pragma unroll
            for (int mt = 0; mt < 2; ++mt)
                #pragma unroll
                for (int r = 0; r < 4; ++r) acc[mt][nt][r] += bv;
        }
    }

    // transform acc (C-layout) -> bf16 h tile. mode 1: relu(bn); mode 3: bn(relu)
    auto transform_store = [&](const float* st, int mode) {
        #pragma unroll
        for (int nt = 0; nt < 8; ++nt) {
            int col = nt * 16 + l16;
            float s = st[col], ss = st[128 + col];
            float mn = s * invM;
            float iv = rsqrtf(ss * invM - mn * mn + BN_EPS);
            #pragma unroll
            for (int mt = 0; mt < 2; ++mt)
                #pragma unroll
                for (int r = 0; r < 4; ++r) {
                    float u = acc[mt][nt][r];
                    float t = (mode == 1) ? fmaxf((u - mn) * iv, 0.f)
                                          : (fmaxf(u, 0.f) - mn) * iv;
                    hw[(mt * 16 + quad * 4 + r) * HBS + col] = f2bf(t);
                }
        }
    };
    // GEMM from bf16 h tile (K=128), W from global (L1/L2-resident).
    auto gemm_h = [&](const unsigned short* Wt, const float* bias, bool gather) {
        #pragma unroll
        for (int i = 0; i < 2; ++i)
            #pragma unroll
            for (int j = 0; j < 8; ++j)
                acc[i][j] = (f32x4){0.f, 0.f, 0.f, 0.f};
        #pragma unroll
        for (int ks = 0; ks < 4; ++ks) {
            int kb = ks * 32 + quad * 8;
            bf16x8 af[2];
            #pragma unroll
            for (int mt = 0; mt < 2; ++mt) {
                int rowl = mt * 16 + l16;
                if (!gather) {
                    af[mt] = *(const bf16x8*)(const void*)&hw[rowl * HBS + kb];
                } else {
                    float v[8];
                    bf2f8(*(const bf16x8*)(const void*)&hw[rowl * HBS + kb], v);
                    int e0 = rs[wave][rowl], e1 = rs[wave][rowl + 1];
                    for (int e = e0; e < e1; ++e) {
                        int sr = ci[wave][e];
                        float t[8];
                        bf2f8(*(const bf16x8*)(const void*)&hw[sr * HBS + kb], t);
                        #pragma unroll
                        for (int j = 0; j < 8; ++j) v[j] += t[j];
                    }
                    af[mt] = quant8(v);
                }
            }
            #pragma unroll
            for (int nt = 0; nt < 8; ++nt) {
                bf16x8 b = *(const bf16x8*)(const void*)&Wt[(size_t)(nt * 16 + l16) * 128 + kb];
                acc[0][nt] = __builtin_amdgcn_mfma_f32_16x16x32_bf16(af[0], b, acc[0][nt], 0, 0, 0);
                acc[1][nt] = __builtin_amdgcn_mfma_f32_16x16x32_bf16(af[1], b, acc[1][nt], 0, 0, 0);
            }
        }
        #pragma unroll
        for (int nt = 0; nt < 8; ++nt) {
            float bv = bias[nt * 16 + l16];
            #pragma unroll
            for (int mt = 0; mt < 2; ++mt)
                #pragma unroll
                for (int r = 0; r < 4; ++r) acc[mt][nt][r] += bv;
        }
    };

    if constexpr (DEPTH >= 2) { transform_store(st1, 1); gemm_h(W12, b12, false); }
    if constexpr (DEPTH >= 3) { transform_store(st2, 3); gemm_h(W21, b21, true);  }
    if constexpr (DEPTH >= 4) { transform_store(st3, 1); gemm_h(W22, b22, false); }

    // ======== stats (+pool) epilogue, per-wave, atomic (no barrier) =========
    constexpr bool RELU_STATS = (DEPTH == 2 || DEPTH == 4);
    #pragma unroll
    for (int nt = 0; nt < 8; ++nt) {
        int col = nt * 16 + l16;
        float ls = 0.f, lq = 0.f, mx = -INFINITY;
        #pragma unroll
        for (int mt = 0; mt < 2; ++mt)
            #pragma unroll
            for (int r = 0; r < 4; ++r) {
                float u = acc[mt][nt][r];
                float ru = fmaxf(u, 0.f);
                float s = RELU_STATS ? ru : u;
                ls += s; lq += s * s;
                if (DEPTH == 4) mx = fmaxf(mx, ru);
            }
        ls += __shfl_xor(ls, 16); lq += __shfl_xor(lq, 16);
        ls += __shfl_xor(ls, 32); lq += __shfl_xor(lq, 32);
        if (DEPTH == 4) {
            mx = fmaxf(mx, __shfl_xor(mx, 16));
            mx = fmaxf(mx, __shfl_xor(mx, 32));
        }
        if (quad == 0) {
            unsafeAtomicAdd(&out_stats[col], ls);
            unsafeAtomicAdd(&out_stats[128 + col], lq);
            if (DEPTH == 4) pool_out[(size_t)(g0 + wave) * 128 + col] = mx;
        }
    }
}

// ---------------------------------------------------------------------------
// Register-A MFMA GEMM for the 8192-row layers. Tile 64 x NT, K <= KSTEPS*32.
// In-place safe.
// ---------------------------------------------------------------------------
template<int KSTEPS, int NT>
__launch_bounds__(256)
__global__ void gemm_rA(const float* __restrict__ A, const float* __restrict__ A2,
                        int lda, int K, int stats_K, int ksplit,
                        const unsigned short* __restrict__ Wt,
                        const float* __restrict__ bias, float* __restrict__ C,
                        const float* __restrict__ in_stats, float inv_sM, int in_mode,
                        float* __restrict__ out_stats, int stats_mode, int out_act)
{
    constexpr int LSTRW = KSTEPS * 32 + 8;
    constexpr int NSUB = NT / 16;
    __shared__ unsigned short Ws_l[NT * LSTRW];
    __shared__ float pm[KSTEPS * 32], pv[KSTEPS * 32];
    __shared__ float red[4][2][NT];

    int tid  = threadIdx.x;
    int wave = tid >> 6;
    int lane = tid & 63;
    int quad = lane >> 4;
    int l16  = lane & 15;
    int m0   = blockIdx.x * 64;

    const bool kvec = ((K & 3) == 0);

    for (int i = tid; i < NT * (KSTEPS * 8); i += 256) {
        int n = i / (KSTEPS * 8), g4 = i % (KSTEPS * 8);
        int k = g4 * 4;
        us4 w = (us4){0, 0, 0, 0};
        if (k < K) {
            const unsigned short* wp = Wt + (size_t)n * K + k;
            if (kvec) w = *(const us4*)wp;
            else {
                w.x = wp[0];
                if (k + 1 < K) w.y = wp[1];
                if (k + 2 < K) w.z = wp[2];
                if (k + 3 < K) w.w = wp[3];
            }
        }
        *(us4*)&Ws_l[n * LSTRW + k] = w;
    }
    if (in_mode) {
        for (int k = tid; k < KSTEPS * 32; k += 256) {
            float mn = 0.f, iv = 1.f;
            if (k < stats_K) {
                float s = in_stats[k], ss = in_stats[stats_K + k];
                mn = s * inv_sM;
                float vr = ss * inv_sM - mn * mn;
                iv = rsqrtf(vr + BN_EPS);
            }
            pm[k] = mn; pv[k] = iv;
        }
    }
    __syncthreads();

    bf16x8 afrag[KSTEPS];
    {
        int row = m0 + wave * 16 + l16;
        const float* ap = A + (size_t)row * lda;
        #pragma unroll
        for (int ks = 0; ks < KSTEPS; ++ks) {
            int kb = ks * 32 + quad * 8;
            float v[8];
            if (kvec) {
                #pragma unroll
                for (int hh = 0; hh < 2; ++hh) {
                    int k = kb + hh * 4;
                    const float* p = (k >= ksplit) ? &A2[(size_t)row * 128 + (k - 128)]
                                                   : &ap[k];
                    float4 f = *(const float4*)p;
                    v[hh * 4 + 0] = f.x; v[hh * 4 + 1] = f.y;
                    v[hh * 4 + 2] = f.z; v[hh * 4 + 3] = f.w;
                }
            } else {
                #pragma unroll
                for (int j = 0; j < 8; ++j) {
                    int k = kb + j;
                    v[j] = (k < K) ? ap[k] : 0.f;
                }
            }
            if (in_mode) {
                #pragma unroll
                for (int j = 0; j < 8; ++j)
                    v[j] = apply_in(v[j], in_mode, pm[kb + j], pv[kb + j]);
            }
            afrag[ks] = quant8(v);
        }
    }

    f32x4 acc[NSUB];
    #pragma unroll
    for (int j = 0; j < NSUB; ++j) acc[j] = (f32x4){0.f, 0.f, 0.f, 0.f};

    #pragma unroll
    for (int ks = 0; ks < KSTEPS; ++ks) {
        #pragma unroll
        for (int nt = 0; nt < NSUB; ++nt) {
            bf16x8 b = *(const bf16x8*)(const void*)&Ws_l[(nt * 16 + l16) * LSTRW + ks * 32 + quad * 8];
            acc[nt] = __builtin_amdgcn_mfma_f32_16x16x32_bf16(afrag[ks], b, acc[nt], 0, 0, 0);
        }
    }

    float ls[NSUB], lq[NSUB];
    #pragma unroll
    for (int nt = 0; nt < NSUB; ++nt) { ls[nt] = 0.f; lq[nt] = 0.f; }

    #pragma unroll
    for (int nt = 0; nt < NSUB; ++nt) {
        int col = nt * 16 + l16;
        float bv = bias[col];
        int rbase = m0 + wave * 16 + quad * 4;
        #pragma unroll
        for (int r = 0; r < 4; ++r) {
            float u = acc[nt][r] + bv;
            if (C) {
                float wv = out_act ? fmaxf(u, 0.f) : u;
                C[(size_t)(rbase + r) * NT + col] = wv;
            }
            if (stats_mode) {
                float s = (stats_mode == 2) ? fmaxf(u, 0.f) : u;
                ls[nt] += s; lq[nt] += s * s;
            }
        }
    }

    if (stats_mode) {
        #pragma unroll
        for (int nt = 0; nt < NSUB; ++nt) {
            float s = ls[nt], q = lq[nt];
            s += __shfl_xor(s, 16); q += __shfl_xor(q, 16);
            s += __shfl_xor(s, 32); q += __shfl_xor(q, 32);
            if (quad == 0) { red[wave][0][nt * 16 + l16] = s; red[wave][1][nt * 16 + l16] = q; }
        }
        __syncthreads();
        if (tid < NT) {
            float s = red[0][0][tid] + red[1][0][tid] + red[2][0][tid] + red[3][0][tid];
            float q = red[0][1][tid] + red[1][1][tid] + red[2][1][tid] + red[3][1][tid];
            unsafeAtomicAdd(&out_stats[tid], s);
            unsafeAtomicAdd(&out_stats[NT + tid], q);
        }
    }
}

// ---------------------------------------------------------------------------
// Cell-branch GEMM (large K): tile 64 x NT, 4 waves x 16 rows, K-chunk 64.
// ---------------------------------------------------------------------------
template<int NT>
__launch_bounds__(256)
__global__ void gemm_cell(const float* __restrict__ A, const unsigned short* __restrict__ Wt,
                          const float* __restrict__ bias, float* __restrict__ C,
                          int M, int K, int N,
                          const float* __restrict__ in_stats, float inv_sM, int in_mode,
                          float* __restrict__ out_stats)
{
    constexpr int NSUB = NT / 16;
    __shared__ unsigned short As_l[64 * 72];
    __shared__ unsigned short Ws_l[NT * 72];
    __shared__ float pm[916], pv[916];
    __shared__ float red[4][2][NT];

    int tid = threadIdx.x;
    int wave = tid >> 6;
    int lane = tid & 63;
    int quad = lane >> 4;
    int l16 = lane & 15;
    int m0 = blockIdx.x * 64, n0 = blockIdx.y * NT;

    if (in_mode) {
        for (int k = tid; k < K; k += 256) {
            float s = in_stats[k], ss = in_stats[K + k];
            float mn = s * inv_sM;
            float vr = ss * inv_sM - mn * mn;
            pm[k] = mn; pv[k] = rsqrtf(vr + BN_EPS);
        }
        __syncthreads();
    }

    f32x4 acc[NSUB];
    #pragma unroll
    for (int j = 0; j < NSUB; ++j) acc[j] = (f32x4){0.f, 0.f, 0.f, 0.f};

    for (int k0 = 0; k0 < K; k0 += 64) {
        for (int i = tid; i < 64 * 16; i += 256) {
            int row = i >> 4, f4 = i & 15;
            int k = k0 + f4 * 4;
            us4 w4 = (us4){0, 0, 0, 0};
            if (k < K) {
                float4 f = *(const float4*)&A[(size_t)(m0 + row) * K + k];
                if (in_mode) {
                    f.x = apply_in(f.x, in_mode, pm[k], pv[k]);
                    f.y = apply_in(f.y, in_mode, pm[k + 1], pv[k + 1]);
                    f.z = apply_in(f.z, in_mode, pm[k + 2], pv[k + 2]);
                    f.w = apply_in(f.w, in_mode, pm[k + 3], pv[k + 3]);
                }
                w4 = (us4){ f2bf(f.x), f2bf(f.y), f2bf(f.z), f2bf(f.w) };
            }
            *(us4*)&As_l[row * 72 + f4 * 4] = w4;
        }
        for (int i = tid; i < NT * 16; i += 256) {
            int nn = i >> 4, kt = i & 15;
            int k = k0 + kt * 4;
            int gn = n0 + nn;
            us4 w4 = (us4){0, 0, 0, 0};
            if (gn < N && k < K) w4 = *(const us4*)&Wt[(size_t)gn * K + k];
            *(us4*)&Ws_l[nn * 72 + kt * 4] = w4;
        }
        __syncthreads();
        int rowb = wave * 16;
        #pragma unroll
        for (int ks = 0; ks < 2; ++ks) {
            bf16x8 a = *(const bf16x8*)(const void*)&As_l[(rowb + l16) * 72 + ks * 32 + quad * 8];
            #pragma unroll
            for (int nt = 0; nt < NSUB; ++nt) {
                bf16x8 b = *(const bf16x8*)(const void*)&Ws_l[(nt * 16 + l16) * 72 + ks * 32 + quad * 8];
                acc[nt] = __builtin_amdgcn_mfma_f32_16x16x32_bf16(a, b, acc[nt], 0, 0, 0);
            }
        }
        __syncthreads();
    }

    float ls[NSUB], lq[NSUB];
    #pragma unroll
    for (int nt = 0; nt < NSUB; ++nt) { ls[nt] = 0.f; lq[nt] = 0.f; }

    #pragma unroll
    for (int nt = 0; nt < NSUB; ++nt) {
        int col = n0 + nt * 16 + l16;
        if (col < N) {
            float bv = bias[col];
            int rbase = m0 + wave * 16 + quad * 4;
            #pragma unroll
            for (int r = 0; r < 4; ++r) {
                float u = acc[nt][r] + bv;
                C[(size_t)(rbase + r) * N + col] = u;
                ls[nt] += u; lq[nt] += u * u;
            }
        }
    }

    #pragma unroll
    for (int nt = 0; nt < NSUB; ++nt) {
        float s = ls[nt], q = lq[nt];
        s += __shfl_xor(s, 16); q += __shfl_xor(q, 16);
        s += __shfl_xor(s, 32); q += __shfl_xor(q, 32);
        if (quad == 0) { red[wave][0][nt * 16 + l16] = s; red[wave][1][nt * 16 + l16] = q; }
    }
    __syncthreads();
    if (tid < NT) {
        int col = n0 + tid;
        if (col < N) {
            float s = red[0][0][tid] + red[1][0][tid] + red[2][0][tid] + red[3][0][tid];
            float q = red[0][1][tid] + red[1][1][tid] + red[2][1][tid] + red[3][1][tid];
            unsafeAtomicAdd(&out_stats[col], s);
            unsafeAtomicAdd(&out_stats[N + col], q);
        }
    }
}

// ---------------------------------------------------------------------------
// Final: y[i] = elu(bn(u[i,:])) . w + b   (K = 64)
// ---------------------------------------------------------------------------
__global__ void final_dot(const float* __restrict__ u, const float* __restrict__ w,
                          const float* __restrict__ b, float* __restrict__ y,
                          const float* __restrict__ stats, float inv_sM)
{
    __shared__ float pmv[64], piv[64], sw[64];
    int tid = threadIdx.x;
    if (tid < 64) {
        float s = stats[tid], ss = stats[64 + tid];
        float mn = s * inv_sM;
        float vr = ss * inv_sM - mn * mn;
        pmv[tid] = mn;
        piv[tid] = rsqrtf(vr + BN_EPS);
        sw[tid] = w[tid];
    }
    __syncthreads();
    int i = blockIdx.x * blockDim.x + tid;
    if (i >= BGRAPH) return;
    float acc = 0.f;
    #pragma unroll
    for (int k = 0; k < 64; ++k) {
        float v = (u[(size_t)i * 64 + k] - pmv[k]) * piv[k];
        v = (v > 0.f) ? v : expm1f(v);
        acc += v * sw[k];
    }
    y[i] = acc + b[0];
}

// ---------------------------------------------------------------------------
// Host driver. 12 launches.
// ---------------------------------------------------------------------------
extern "C" void kernel_launch(void* const* d_in, const int* in_sizes, int n_in,
                              void* d_out, int out_size, void* d_ws, size_t ws_size,
                              hipStream_t stream)
{
    const float* cell   = (const float*)d_in[0];
    const float* drug_x = (const float*)d_in[1];
    const int*   eidx   = (const int*)d_in[2];
    const float* ce1w = (const float*)d_in[4];  const float* ce1b = (const float*)d_in[5];
    const float* ce2w = (const float*)d_in[6];  const float* ce2b = (const float*)d_in[7];
    const float* ce3w = (const float*)d_in[8];  const float* ce3b = (const float*)d_in[9];
    const float* g11w = (const float*)d_in[10]; const float* g11b = (const float*)d_in[11];
    const float* g12w = (const float*)d_in[12]; const float* g12b = (const float*)d_in[13];
    const float* g21w = (const float*)d_in[14]; const float* g21b = (const float*)d_in[15];
    const float* g22w = (const float*)d_in[16]; const float* g22b = (const float*)d_in[17];
    const float* d1w  = (const float*)d_in[18]; const float* d1b  = (const float*)d_in[19];
    const float* d2w  = (const float*)d_in[20]; const float* d2b  = (const float*)d_in[21];
    const float* f1w  = (const float*)d_in[22]; const float* f1b  = (const float*)d_in[23];
    const float* f2w  = (const float*)d_in[24]; const float* f2b  = (const float*)d_in[25];
    const float* f3w  = (const float*)d_in[26]; const float* f3b  = (const float*)d_in[27];

    const int* src = eidx;
    const int* dst = eidx + NEDGE;
    float* out = (float*)d_out;

    const float INV_N = 1.f / (float)NNODE;
    const float INV_B = 1.f / (float)BGRAPH;
    const int KBIG = 1 << 30;

    // ---- workspace layout ----
    float* ws   = (float*)d_ws;
    float* big  = ws;
    float* aux  = ws + (size_t)NNODE * 128;
    float* sb   = aux + (size_t)NNODE * 9;              // 10*1032 stats floats
    unsigned short* wtb = (unsigned short*)(sb + 10 * 1032);
    auto ST = [&](int i) { return sb + (size_t)i * 1032; };
    float* st_u1    = ST(0);
    float* st_u2rel = ST(1);
    float* st_u3    = ST(2);
    float* st_u4rel = ST(3);
    float* st_c1    = ST(4);
    float* st_c2    = ST(5);
    float* st_c3    = ST(6);
    float* st_d1    = ST(7);
    float* st_f1    = ST(8);
    float* st_f2    = ST(9);

    struct WDef { const float* w; int K; int N; };
    WDef wd[11] = {
        {ce1w, CELLD, 516}, {ce2w, 516, 256}, {ce3w, 256, 128},
        {g11w, 9, 128}, {g12w, 128, 128}, {g21w, 128, 128}, {g22w, 128, 128},
        {d1w, 128, 128}, {d2w, 128, 128}, {f1w, 256, 128}, {f2w, 128, 64}
    };
    SetupArgs sa;
    int off = 0;
    unsigned short* wt[11];
    for (int i = 0; i < 11; ++i) {
        wt[i] = wtb + off;
        sa.s[i] = TSeg{ wd[i].w, wt[i], wd[i].K, wd[i].N, off };
        off += wd[i].K * wd[i].N;
    }
    sa.tTotal = off;
    sa.tBlocks = (off + 255) / 256;
    sa.zb = sb; sa.zTotal = 10 * 1032; sa.zBlocks = (10 * 1032 + 255) / 256;
    sa.src = src; sa.dst = dst;

    int csr_off = (off + 7) & ~7;
    int* row_start = (int*)(wtb + csr_off);
    int* col_idx   = row_start + (size_t)BGRAPH * 33;
    sa.row_start = row_start; sa.col_idx = col_idx;

    float* c1    = big;
    float* c2    = c1 + (size_t)BGRAPH * 516;
    float* c3u   = c2 + (size_t)BGRAPH * 256;
    float* dbuf  = c3u + (size_t)BGRAPH * 128;
    float* d2buf = dbuf + (size_t)BGRAPH * 128;
    float* f1o   = d2buf + (size_t)BGRAPH * 128;
    float* f2o   = f1o + (size_t)BGRAPH * 128;
    float* pbuf  = aux;

    setup_all<<<sa.tBlocks + sa.zBlocks + BGRAPH / 4, 256, 0, stream>>>(sa);

    // ================= GIN branch: recompute chain, barrier-free ============
    gin_chain<1><<<BGRAPH / 4, 256, 0, stream>>>(
        drug_x, row_start, col_idx, wt[3], g11b, wt[4], g12b, wt[5], g21b, wt[6], g22b,
        st_u1, st_u2rel, st_u3, INV_N, st_u1, nullptr);
    gin_chain<2><<<BGRAPH / 4, 256, 0, stream>>>(
        drug_x, row_start, col_idx, wt[3], g11b, wt[4], g12b, wt[5], g21b, wt[6], g22b,
        st_u1, st_u2rel, st_u3, INV_N, st_u2rel, nullptr);
    gin_chain<3><<<BGRAPH / 4, 256, 0, stream>>>(
        drug_x, row_start, col_idx, wt[3], g11b, wt[4], g12b, wt[5], g21b, wt[6], g22b,
        st_u1, st_u2rel, st_u3, INV_N, st_u3, nullptr);
    gin_chain<4><<<BGRAPH / 4, 256, 0, stream>>>(
        drug_x, row_start, col_idx, wt[3], g11b, wt[4], g12b, wt[5], g21b, wt[6], g22b,
        st_u1, st_u2rel, st_u3, INV_N, st_u4rel, pbuf);

    // ================= cell branch ===========================================
    gemm_cell<128><<<dim3(BGRAPH / 64, 5), 256, 0, stream>>>(
        cell, wt[0], ce1b, c1, BGRAPH, CELLD, 516, nullptr, 0.f, 0, st_c1);
    gemm_cell<64><<<dim3(BGRAPH / 64, 4), 256, 0, stream>>>(
        c1, wt[1], ce2b, c2, BGRAPH, 516, 256, st_c1, INV_B, 1, st_c2);
    gemm_rA<8, 128><<<BGRAPH / 64, 256, 0, stream>>>(
        c2, nullptr, 256, 256, 256, KBIG, wt[2], ce3b, c3u,
        st_c2, INV_B, 1, st_c3, 1, 0);

    // ================= d branch ==============================================
    gemm_rA<4, 128><<<BGRAPH / 64, 256, 0, stream>>>(
        pbuf, nullptr, 128, 128, 128, KBIG, wt[7], d1b, dbuf,
        st_u4rel, INV_N, 3, st_d1, 1, 0);
    gemm_rA<4, 128><<<BGRAPH / 64, 256, 0, stream>>>(
        dbuf, nullptr, 128, 128, 128, KBIG, wt[8], d2b, d2buf,
        st_d1, INV_B, 1, nullptr, 0, 1);

    // ================= head ==================================================
    gemm_rA<8, 128><<<BGRAPH / 64, 256, 0, stream>>>(
        c3u, d2buf, 128, 256, 128, 128, wt[9], f1b, f1o,
        st_c3, INV_B, 1, st_f1, 1, 0);
    gemm_rA<4, 64><<<BGRAPH / 64, 256, 0, stream>>>(
        f1o, nullptr, 128, 128, 128, KBIG, wt[10], f2b, f2o,
        st_f1, INV_B, 2, st_f2, 1, 0);
    final_dot<<<BGRAPH / 256, 256, 0, stream>>>(f2o, f3w, f3b, out, st_f2, INV_B);
}

// Round 12
// 774.056 us; speedup vs baseline: 2.2503x; 2.2503x over previous
//
#include <hip/hip_runtime.h>
#include <hip/hip_bf16.h>
#include <math.h>

// Problem constants (from reference)
#define BGRAPH 8192
#define NPG 32
#define EPG 64
#define NNODE (BGRAPH * NPG)   // 262144
#define NEDGE (BGRAPH * EPG)   // 524288
#define CELLD 908
#define BN_EPS 1e-5f

typedef __attribute__((ext_vector_type(8))) short bf16x8;   // 8 bf16 = 4 VGPRs
typedef __attribute__((ext_vector_type(4))) float f32x4;
typedef __attribute__((ext_vector_type(4))) unsigned short us4;

__device__ __forceinline__ unsigned short f2bf(float f)
{
    unsigned int u = __float_as_uint(f);
    u = (u + 0x7FFFu + ((u >> 16) & 1u)) >> 16;   // RNE
    return (unsigned short)u;
}

__device__ __forceinline__ bf16x8 quant8(const float v[8])
{
    union { bf16x8 b; unsigned short u[8]; } fr;
    #pragma unroll
    for (int j = 0; j < 8; ++j) fr.u[j] = f2bf(v[j]);
    return fr.b;
}

__device__ __forceinline__ void bf2f8(bf16x8 b, float v[8])
{
    union { bf16x8 bb; unsigned short u[8]; } x; x.bb = b;
    #pragma unroll
    for (int j = 0; j < 8; ++j) v[j] = __uint_as_float((unsigned)x.u[j] << 16);
}

// in_mode: 0=raw, 1=relu((x-m)*iv), 2=elu((x-m)*iv), 3=(relu(x)-m)*iv
__device__ __forceinline__ float apply_in(float v, int mode, float mn, float iv)
{
    if (mode == 1)      { v = (v - mn) * iv; v = fmaxf(v, 0.f); }
    else if (mode == 2) { v = (v - mn) * iv; v = (v > 0.f) ? v : expm1f(v); }
    else if (mode == 3) { v = fmaxf(v, 0.f); v = (v - mn) * iv; }
    return v;
}

// ---------------------------------------------------------------------------
// Merged setup: weight transpose+bf16, stats zero, per-graph in-edge CSR.
// ---------------------------------------------------------------------------
struct TSeg { const float* w; unsigned short* wt; int K; int N; int off; };
struct SetupArgs {
    TSeg s[11]; int tTotal; int tBlocks;
    float* zb; int zTotal; int zBlocks;
    const int* src; const int* dst; int* row_start; int* col_idx;
};

__global__ void setup_all(SetupArgs a)
{
    int b = blockIdx.x;
    int tid = threadIdx.x;
    if (b < a.tBlocks) {
        int i = b * 256 + tid;
        if (i < a.tTotal) {
            int j = 0;
            while (j < 10 && i >= a.s[j + 1].off) ++j;
            int idx = i - a.s[j].off;
            int K = a.s[j].K, N = a.s[j].N;
            int n = idx / K, k = idx - n * K;
            a.s[j].wt[idx] = f2bf(a.s[j].w[(size_t)k * N + n]);
        }
        return;
    }
    b -= a.tBlocks;
    if (b < a.zBlocks) {
        int i = b * 256 + tid;
        if (i < a.zTotal) a.zb[i] = 0.f;
        return;
    }
    b -= a.zBlocks;
    // CSR build: 4 graphs per block
    __shared__ int cnt[4][32], fill[4][32], rsl[4][33];
    int gl = tid >> 6, e = tid & 63;
    int g = b * 4 + gl;
    if (e < 32) { cnt[gl][e] = 0; fill[gl][e] = 0; }
    __syncthreads();
    int s = a.src[g * EPG + e] - g * NPG;
    int d = a.dst[g * EPG + e] - g * NPG;
    atomicAdd(&cnt[gl][d], 1);
    __syncthreads();
    if (e == 0) {
        int acc = 0;
        for (int i = 0; i < 32; ++i) { rsl[gl][i] = acc; acc += cnt[gl][i]; }
        rsl[gl][32] = acc;
    }
    __syncthreads();
    int pos = rsl[gl][d] + atomicAdd(&fill[gl][d], 1);
    a.col_idx[g * EPG + pos] = s;
    if (e < 33) a.row_start[g * 33 + e] = rsl[gl][e];
}

// ---------------------------------------------------------------------------
// GIN chain by RECOMPUTE: block = 4 graphs, wave = 1 graph. Cooperative
// staging (1 barrier), then every stage is WAVE-PRIVATE (h tile per wave,
// bf16) -> NO inter-stage barriers. Stats: per-wave shuffle reduce ->
// block-level LDS reduce (red overlaid on w11l, separated by barrier) ->
// 256 atomics per BLOCK (low contention). LDS 40512 B -> 4 blocks/CU.
// Chain: a = x + agg(x); u1 = a@W11+b11 [stats raw @D1]
//        u2 = relu(bn(u1))@W12+b12     [stats relu @D2]
//        h  = bn(relu(u2)); u3 = (h+agg(h))@W21+b21 [stats raw @D3]
//        u4 = relu(bn(u3))@W22+b22     [stats relu + pool @D4]
// ---------------------------------------------------------------------------
#define HBS 136   // bf16 h row stride (ushorts): 272 B, 16B-aligned

template<int DEPTH>
__launch_bounds__(256)
__global__ void gin_chain(const float* __restrict__ drug_x,
                          const int* __restrict__ row_start,
                          const int* __restrict__ col_idx,
                          const unsigned short* __restrict__ W11,   // [128][9]
                          const float* __restrict__ b11,
                          const unsigned short* __restrict__ W12, const float* __restrict__ b12,
                          const unsigned short* __restrict__ W21, const float* __restrict__ b21,
                          const unsigned short* __restrict__ W22, const float* __restrict__ b22,
                          const float* __restrict__ st1,
                          const float* __restrict__ st2,
                          const float* __restrict__ st3,
                          float invM,
                          float* __restrict__ out_stats,
                          float* __restrict__ pool_out)
{
    __shared__ __align__(16) unsigned short h[4 * 32 * HBS];    // 34816 B
    __shared__ __align__(16) unsigned char ubuf[4096];          // w11l <-> red overlay
    __shared__ int rs[4][36];                                   // 576 B
    __shared__ int ci[4][64];                                   // 1024 B

    unsigned short* w11l = (unsigned short*)ubuf;   // [128][16], stage 1 only
    float* red = (float*)ubuf;                      // [(wave*2+s)*128 + col], epilogue

    int tid  = threadIdx.x;
    int wave = tid >> 6;
    int lane = tid & 63;
    int quad = lane >> 4;
    int l16  = lane & 15;
    int g0   = blockIdx.x * 4;
    unsigned short* hw = h + wave * (32 * HBS);
    float* xw = (float*)hw;          // stage-1 fp32 x tile (32x16), overlaid

    // ---- cooperative staging (single barrier) ----
    for (int i = tid; i < 128 * 16; i += 256) {
        int n = i >> 4, k = i & 15;
        w11l[i] = (k < 9) ? W11[n * 9 + k] : (unsigned short)0;
    }
    if (tid < 132) {
        int gl = tid / 33, idx = tid - gl * 33;
        rs[gl][idx] = row_start[(g0 + gl) * 33 + idx];
    }
    {
        int gl = tid >> 6, e = tid & 63;
        ci[gl][e] = col_idx[(g0 + gl) * EPG + e];
    }
    {
        const float* xg = drug_x + (size_t)(g0 + wave) * 32 * 9;
        for (int i = lane; i < 32 * 16; i += 64) {
            int rr = i >> 4, c = i & 15;
            xw[i] = (c < 9) ? xg[rr * 9 + c] : 0.f;     // wave-private region
        }
    }
    __syncthreads();

    f32x4 acc[2][8];
    #pragma unroll
    for (int i = 0; i < 2; ++i)
        #pragma unroll
        for (int j = 0; j < 8; ++j)
            acc[i][j] = (f32x4){0.f, 0.f, 0.f, 0.f};

    // ======== stage 1: u1 = (x + agg(x)) @ W11 + b11 (fp32 gather) ==========
    {
        bf16x8 af[2];
        #pragma unroll
        for (int mt = 0; mt < 2; ++mt) {
            int rowl = mt * 16 + l16;
            float v[8] = {0, 0, 0, 0, 0, 0, 0, 0};
            if (quad < 2) {
                float4 lo = *(const float4*)&xw[rowl * 16 + quad * 8];
                float4 hi = *(const float4*)&xw[rowl * 16 + quad * 8 + 4];
                v[0] = lo.x; v[1] = lo.y; v[2] = lo.z; v[3] = lo.w;
                v[4] = hi.x; v[5] = hi.y; v[6] = hi.z; v[7] = hi.w;
                int e0 = rs[wave][rowl], e1 = rs[wave][rowl + 1];
                for (int e = e0; e < e1; ++e) {
                    int sr = ci[wave][e];
                    float4 l2 = *(const float4*)&xw[sr * 16 + quad * 8];
                    float4 h2 = *(const float4*)&xw[sr * 16 + quad * 8 + 4];
                    v[0] += l2.x; v[1] += l2.y; v[2] += l2.z; v[3] += l2.w;
                    v[4] += h2.x; v[5] += h2.y; v[6] += h2.z; v[7] += h2.w;
                }
            }
            af[mt] = quant8(v);
        }
        #pragma unroll
        for (int nt = 0; nt < 8; ++nt) {
            bf16x8 b;
            if (quad < 2) b = *(const bf16x8*)(const void*)&w11l[(nt * 16 + l16) * 16 + quad * 8];
            else { float z[8] = {0,0,0,0,0,0,0,0}; b = quant8(z); }
            acc[0][nt] = __builtin_amdgcn_mfma_f32_16x16x32_bf16(af[0], b, acc[0][nt], 0, 0, 0);
            acc[1][nt] = __builtin_amdgcn_mfma_f32_16x16x32_bf16(af[1], b, acc[1][nt], 0, 0, 0);
        }
        #pragma unroll
        for (int nt = 0; nt < 8; ++nt) {
            float bv = b11[nt * 16 + l16];
            #pragma unroll
            for (int mt = 0; mt < 2; ++mt)
                #pragma unroll
                for (int r = 0; r < 4; ++r) acc[mt][nt][r] += bv;
        }
    }

    // transform acc (C-layout) -> bf16 h tile. mode 1: relu(bn); mode 3: bn(relu)
    auto transform_store = [&](const float* st, int mode) {
        #pragma unroll
        for (int nt = 0; nt < 8; ++nt) {
            int col = nt * 16 + l16;
            float s = st[col], ss = st[128 + col];
            float mn = s * invM;
            float iv = rsqrtf(ss * invM - mn * mn + BN_EPS);
            #pragma unroll
            for (int mt = 0; mt < 2; ++mt)
                #pragma unroll
                for (int r = 0; r < 4; ++r) {
                    float u = acc[mt][nt][r];
                    float t = (mode == 1) ? fmaxf((u - mn) * iv, 0.f)
                                          : (fmaxf(u, 0.f) - mn) * iv;
                    hw[(mt * 16 + quad * 4 + r) * HBS + col] = f2bf(t);
                }
        }
    };
    // GEMM from bf16 h tile (K=128), W from global (L1/L2-resident).
    auto gemm_h = [&](const unsigned short* Wt, const float* bias, bool gather) {
        #pragma unroll
        for (int i = 0; i < 2; ++i)
            #pragma unroll
            for (int j = 0; j < 8; ++j)
                acc[i][j] = (f32x4){0.f, 0.f, 0.f, 0.f};
        #pragma unroll
        for (int ks = 0; ks < 4; ++ks) {
            int kb = ks * 32 + quad * 8;
            bf16x8 af[2];
            #pragma unroll
            for (int mt = 0; mt < 2; ++mt) {
                int rowl = mt * 16 + l16;
                if (!gather) {
                    af[mt] = *(const bf16x8*)(const void*)&hw[rowl * HBS + kb];
                } else {
                    float v[8];
                    bf2f8(*(const bf16x8*)(const void*)&hw[rowl * HBS + kb], v);
                    int e0 = rs[wave][rowl], e1 = rs[wave][rowl + 1];
                    for (int e = e0; e < e1; ++e) {
                        int sr = ci[wave][e];
                        float t[8];
                        bf2f8(*(const bf16x8*)(const void*)&hw[sr * HBS + kb], t);
                        #pragma unroll
                        for (int j = 0; j < 8; ++j) v[j] += t[j];
                    }
                    af[mt] = quant8(v);
                }
            }
            #pragma unroll
            for (int nt = 0; nt < 8; ++nt) {
                bf16x8 b = *(const bf16x8*)(const void*)&Wt[(size_t)(nt * 16 + l16) * 128 + kb];
                acc[0][nt] = __builtin_amdgcn_mfma_f32_16x16x32_bf16(af[0], b, acc[0][nt], 0, 0, 0);
                acc[1][nt] = __builtin_amdgcn_mfma_f32_16x16x32_bf16(af[1], b, acc[1][nt], 0, 0, 0);
            }
        }
        #pragma unroll
        for (int nt = 0; nt < 8; ++nt) {
            float bv = bias[nt * 16 + l16];
            #pragma unroll
            for (int mt = 0; mt < 2; ++mt)
                #pragma unroll
                for (int r = 0; r < 4; ++r) acc[mt][nt][r] += bv;
        }
    };

    if constexpr (DEPTH >= 2) { transform_store(st1, 1); gemm_h(W12, b12, false); }
    if constexpr (DEPTH >= 3) { transform_store(st2, 3); gemm_h(W21, b21, true);  }
    if constexpr (DEPTH >= 4) { transform_store(st3, 1); gemm_h(W22, b22, false); }

    // ======== stats (+pool) epilogue: wave reduce -> block reduce -> atomics =
    constexpr bool RELU_STATS = (DEPTH == 2 || DEPTH == 4);
    float ls[8], lq[8];
    #pragma unroll
    for (int nt = 0; nt < 8; ++nt) {
        int col = nt * 16 + l16;
        float s0 = 0.f, q0 = 0.f, mx = -INFINITY;
        #pragma unroll
        for (int mt = 0; mt < 2; ++mt)
            #pragma unroll
            for (int r = 0; r < 4; ++r) {
                float u = acc[mt][nt][r];
                float ru = fmaxf(u, 0.f);
                float s = RELU_STATS ? ru : u;
                s0 += s; q0 += s * s;
                if (DEPTH == 4) mx = fmaxf(mx, ru);
            }
        ls[nt] = s0; lq[nt] = q0;
        if (DEPTH == 4) {
            mx = fmaxf(mx, __shfl_xor(mx, 16));
            mx = fmaxf(mx, __shfl_xor(mx, 32));
            if (quad == 0) pool_out[(size_t)(g0 + wave) * 128 + col] = mx;
        }
    }
    __syncthreads();   // all waves done with w11l before red overlay
    #pragma unroll
    for (int nt = 0; nt < 8; ++nt) {
        float s = ls[nt], q = lq[nt];
        s += __shfl_xor(s, 16); q += __shfl_xor(q, 16);
        s += __shfl_xor(s, 32); q += __shfl_xor(q, 32);
        if (quad == 0) {
            int col = nt * 16 + l16;
            red[(wave * 2 + 0) * 128 + col] = s;
            red[(wave * 2 + 1) * 128 + col] = q;
        }
    }
    __syncthreads();
    if (tid < 128) {
        float s = red[0 * 128 + tid] + red[2 * 128 + tid] + red[4 * 128 + tid] + red[6 * 128 + tid];
        float q = red[1 * 128 + tid] + red[3 * 128 + tid] + red[5 * 128 + tid] + red[7 * 128 + tid];
        unsafeAtomicAdd(&out_stats[tid], s);
        unsafeAtomicAdd(&out_stats[128 + tid], q);
    }
}

// ---------------------------------------------------------------------------
// Register-A MFMA GEMM for the 8192-row layers. Tile 64 x NT, K <= KSTEPS*32.
// In-place safe.
// ---------------------------------------------------------------------------
template<int KSTEPS, int NT>
__launch_bounds__(256)
__global__ void gemm_rA(const float* __restrict__ A, const float* __restrict__ A2,
                        int lda, int K, int stats_K, int ksplit,
                        const unsigned short* __restrict__ Wt,
                        const float* __restrict__ bias, float* __restrict__ C,
                        const float* __restrict__ in_stats, float inv_sM, int in_mode,
                        float* __restrict__ out_stats, int stats_mode, int out_act)
{
    constexpr int LSTRW = KSTEPS * 32 + 8;
    constexpr int NSUB = NT / 16;
    __shared__ unsigned short Ws_l[NT * LSTRW];
    __shared__ float pm[KSTEPS * 32], pv[KSTEPS * 32];
    __shared__ float red[4][2][NT];

    int tid  = threadIdx.x;
    int wave = tid >> 6;
    int lane = tid & 63;
    int quad = lane >> 4;
    int l16  = lane & 15;
    int m0   = blockIdx.x * 64;

    const bool kvec = ((K & 3) == 0);

    for (int i = tid; i < NT * (KSTEPS * 8); i += 256) {
        int n = i / (KSTEPS * 8), g4 = i % (KSTEPS * 8);
        int k = g4 * 4;
        us4 w = (us4){0, 0, 0, 0};
        if (k < K) {
            const unsigned short* wp = Wt + (size_t)n * K + k;
            if (kvec) w = *(const us4*)wp;
            else {
                w.x = wp[0];
                if (k + 1 < K) w.y = wp[1];
                if (k + 2 < K) w.z = wp[2];
                if (k + 3 < K) w.w = wp[3];
            }
        }
        *(us4*)&Ws_l[n * LSTRW + k] = w;
    }
    if (in_mode) {
        for (int k = tid; k < KSTEPS * 32; k += 256) {
            float mn = 0.f, iv = 1.f;
            if (k < stats_K) {
                float s = in_stats[k], ss = in_stats[stats_K + k];
                mn = s * inv_sM;
                float vr = ss * inv_sM - mn * mn;
                iv = rsqrtf(vr + BN_EPS);
            }
            pm[k] = mn; pv[k] = iv;
        }
    }
    __syncthreads();

    bf16x8 afrag[KSTEPS];
    {
        int row = m0 + wave * 16 + l16;
        const float* ap = A + (size_t)row * lda;
        #pragma unroll
        for (int ks = 0; ks < KSTEPS; ++ks) {
            int kb = ks * 32 + quad * 8;
            float v[8];
            if (kvec) {
                #pragma unroll
                for (int hh = 0; hh < 2; ++hh) {
                    int k = kb + hh * 4;
                    const float* p = (k >= ksplit) ? &A2[(size_t)row * 128 + (k - 128)]
                                                   : &ap[k];
                    float4 f = *(const float4*)p;
                    v[hh * 4 + 0] = f.x; v[hh * 4 + 1] = f.y;
                    v[hh * 4 + 2] = f.z; v[hh * 4 + 3] = f.w;
                }
            } else {
                #pragma unroll
                for (int j = 0; j < 8; ++j) {
                    int k = kb + j;
                    v[j] = (k < K) ? ap[k] : 0.f;
                }
            }
            if (in_mode) {
                #pragma unroll
                for (int j = 0; j < 8; ++j)
                    v[j] = apply_in(v[j], in_mode, pm[kb + j], pv[kb + j]);
            }
            afrag[ks] = quant8(v);
        }
    }

    f32x4 acc[NSUB];
    #pragma unroll
    for (int j = 0; j < NSUB; ++j) acc[j] = (f32x4){0.f, 0.f, 0.f, 0.f};

    #pragma unroll
    for (int ks = 0; ks < KSTEPS; ++ks) {
        #pragma unroll
        for (int nt = 0; nt < NSUB; ++nt) {
            bf16x8 b = *(const bf16x8*)(const void*)&Ws_l[(nt * 16 + l16) * LSTRW + ks * 32 + quad * 8];
            acc[nt] = __builtin_amdgcn_mfma_f32_16x16x32_bf16(afrag[ks], b, acc[nt], 0, 0, 0);
        }
    }

    float ls[NSUB], lq[NSUB];
    #pragma unroll
    for (int nt = 0; nt < NSUB; ++nt) { ls[nt] = 0.f; lq[nt] = 0.f; }

    #pragma unroll
    for (int nt = 0; nt < NSUB; ++nt) {
        int col = nt * 16 + l16;
        float bv = bias[col];
        int rbase = m0 + wave * 16 + quad * 4;
        #pragma unroll
        for (int r = 0; r < 4; ++r) {
            float u = acc[nt][r] + bv;
            if (C) {
                float wv = out_act ? fmaxf(u, 0.f) : u;
                C[(size_t)(rbase + r) * NT + col] = wv;
            }
            if (stats_mode) {
                float s = (stats_mode == 2) ? fmaxf(u, 0.f) : u;
                ls[nt] += s; lq[nt] += s * s;
            }
        }
    }

    if (stats_mode) {
        #pragma unroll
        for (int nt = 0; nt < NSUB; ++nt) {
            float s = ls[nt], q = lq[nt];
            s += __shfl_xor(s, 16); q += __shfl_xor(q, 16);
            s += __shfl_xor(s, 32); q += __shfl_xor(q, 32);
            if (quad == 0) { red[wave][0][nt * 16 + l16] = s; red[wave][1][nt * 16 + l16] = q; }
        }
        __syncthreads();
        if (tid < NT) {
            float s = red[0][0][tid] + red[1][0][tid] + red[2][0][tid] + red[3][0][tid];
            float q = red[0][1][tid] + red[1][1][tid] + red[2][1][tid] + red[3][1][tid];
            unsafeAtomicAdd(&out_stats[tid], s);
            unsafeAtomicAdd(&out_stats[NT + tid], q);
        }
    }
}

// ---------------------------------------------------------------------------
// Cell-branch GEMM (large K): tile 64 x NT, 4 waves x 16 rows, K-chunk 64.
// ---------------------------------------------------------------------------
template<int NT>
__launch_bounds__(256)
__global__ void gemm_cell(const float* __restrict__ A, const unsigned short* __restrict__ Wt,
                          const float* __restrict__ bias, float* __restrict__ C,
                          int M, int K, int N,
                          const float* __restrict__ in_stats, float inv_sM, int in_mode,
                          float* __restrict__ out_stats)
{
    constexpr int NSUB = NT / 16;
    __shared__ unsigned short As_l[64 * 72];
    __shared__ unsigned short Ws_l[NT * 72];
    __shared__ float pm[916], pv[916];
    __shared__ float red[4][2][NT];

    int tid = threadIdx.x;
    int wave = tid >> 6;
    int lane = tid & 63;
    int quad = lane >> 4;
    int l16 = lane & 15;
    int m0 = blockIdx.x * 64, n0 = blockIdx.y * NT;

    if (in_mode) {
        for (int k = tid; k < K; k += 256) {
            float s = in_stats[k], ss = in_stats[K + k];
            float mn = s * inv_sM;
            float vr = ss * inv_sM - mn * mn;
            pm[k] = mn; pv[k] = rsqrtf(vr + BN_EPS);
        }
        __syncthreads();
    }

    f32x4 acc[NSUB];
    #pragma unroll
    for (int j = 0; j < NSUB; ++j) acc[j] = (f32x4){0.f, 0.f, 0.f, 0.f};

    for (int k0 = 0; k0 < K; k0 += 64) {
        for (int i = tid; i < 64 * 16; i += 256) {
            int row = i >> 4, f4 = i & 15;
            int k = k0 + f4 * 4;
            us4 w4 = (us4){0, 0, 0, 0};
            if (k < K) {
                float4 f = *(const float4*)&A[(size_t)(m0 + row) * K + k];
                if (in_mode) {
                    f.x = apply_in(f.x, in_mode, pm[k], pv[k]);
                    f.y = apply_in(f.y, in_mode, pm[k + 1], pv[k + 1]);
                    f.z = apply_in(f.z, in_mode, pm[k + 2], pv[k + 2]);
                    f.w = apply_in(f.w, in_mode, pm[k + 3], pv[k + 3]);
                }
                w4 = (us4){ f2bf(f.x), f2bf(f.y), f2bf(f.z), f2bf(f.w) };
            }
            *(us4*)&As_l[row * 72 + f4 * 4] = w4;
        }
        for (int i = tid; i < NT * 16; i += 256) {
            int nn = i >> 4, kt = i & 15;
            int k = k0 + kt * 4;
            int gn = n0 + nn;
            us4 w4 = (us4){0, 0, 0, 0};
            if (gn < N && k < K) w4 = *(const us4*)&Wt[(size_t)gn * K + k];
            *(us4*)&Ws_l[nn * 72 + kt * 4] = w4;
        }
        __syncthreads();
        int rowb = wave * 16;
        #pragma unroll
        for (int ks = 0; ks < 2; ++ks) {
            bf16x8 a = *(const bf16x8*)(const void*)&As_l[(rowb + l16) * 72 + ks * 32 + quad * 8];
            #pragma unroll
            for (int nt = 0; nt < NSUB; ++nt) {
                bf16x8 b = *(const bf16x8*)(const void*)&Ws_l[(nt * 16 + l16) * 72 + ks * 32 + quad * 8];
                acc[nt] = __builtin_amdgcn_mfma_f32_16x16x32_bf16(a, b, acc[nt], 0, 0, 0);
            }
        }
        __syncthreads();
    }

    float ls[NSUB], lq[NSUB];
    #pragma unroll
    for (int nt = 0; nt < NSUB; ++nt) { ls[nt] = 0.f; lq[nt] = 0.f; }

    #pragma unroll
    for (int nt = 0; nt < NSUB; ++nt) {
        int col = n0 + nt * 16 + l16;
        if (col < N) {
            float bv = bias[col];
            int rbase = m0 + wave * 16 + quad * 4;
            #pragma unroll
            for (int r = 0; r < 4; ++r) {
                float u = acc[nt][r] + bv;
                C[(size_t)(rbase + r) * N + col] = u;
                ls[nt] += u; lq[nt] += u * u;
            }
        }
    }

    #pragma unroll
    for (int nt = 0; nt < NSUB; ++nt) {
        float s = ls[nt], q = lq[nt];
        s += __shfl_xor(s, 16); q += __shfl_xor(q, 16);
        s += __shfl_xor(s, 32); q += __shfl_xor(q, 32);
        if (quad == 0) { red[wave][0][nt * 16 + l16] = s; red[wave][1][nt * 16 + l16] = q; }
    }
    __syncthreads();
    if (tid < NT) {
        int col = n0 + tid;
        if (col < N) {
            float s = red[0][0][tid] + red[1][0][tid] + red[2][0][tid] + red[3][0][tid];
            float q = red[0][1][tid] + red[1][1][tid] + red[2][1][tid] + red[3][1][tid];
            unsafeAtomicAdd(&out_stats[col], s);
            unsafeAtomicAdd(&out_stats[N + col], q);
        }
    }
}

// ---------------------------------------------------------------------------
// Final: y[i] = elu(bn(u[i,:])) . w + b   (K = 64)
// ---------------------------------------------------------------------------
__global__ void final_dot(const float* __restrict__ u, const float* __restrict__ w,
                          const float* __restrict__ b, float* __restrict__ y,
                          const float* __restrict__ stats, float inv_sM)
{
    __shared__ float pmv[64], piv[64], sw[64];
    int tid = threadIdx.x;
    if (tid < 64) {
        float s = stats[tid], ss = stats[64 + tid];
        float mn = s * inv_sM;
        float vr = ss * inv_sM - mn * mn;
        pmv[tid] = mn;
        piv[tid] = rsqrtf(vr + BN_EPS);
        sw[tid] = w[tid];
    }
    __syncthreads();
    int i = blockIdx.x * blockDim.x + tid;
    if (i >= BGRAPH) return;
    float acc = 0.f;
    #pragma unroll
    for (int k = 0; k < 64; ++k) {
        float v = (u[(size_t)i * 64 + k] - pmv[k]) * piv[k];
        v = (v > 0.f) ? v : expm1f(v);
        acc += v * sw[k];
    }
    y[i] = acc + b[0];
}

// ---------------------------------------------------------------------------
// Host driver. 12 launches.
// ---------------------------------------------------------------------------
extern "C" void kernel_launch(void* const* d_in, const int* in_sizes, int n_in,
                              void* d_out, int out_size, void* d_ws, size_t ws_size,
                              hipStream_t stream)
{
    const float* cell   = (const float*)d_in[0];
    const float* drug_x = (const float*)d_in[1];
    const int*   eidx   = (const int*)d_in[2];
    const float* ce1w = (const float*)d_in[4];  const float* ce1b = (const float*)d_in[5];
    const float* ce2w = (const float*)d_in[6];  const float* ce2b = (const float*)d_in[7];
    const float* ce3w = (const float*)d_in[8];  const float* ce3b = (const float*)d_in[9];
    const float* g11w = (const float*)d_in[10]; const float* g11b = (const float*)d_in[11];
    const float* g12w = (const float*)d_in[12]; const float* g12b = (const float*)d_in[13];
    const float* g21w = (const float*)d_in[14]; const float* g21b = (const float*)d_in[15];
    const float* g22w = (const float*)d_in[16]; const float* g22b = (const float*)d_in[17];
    const float* d1w  = (const float*)d_in[18]; const float* d1b  = (const float*)d_in[19];
    const float* d2w  = (const float*)d_in[20]; const float* d2b  = (const float*)d_in[21];
    const float* f1w  = (const float*)d_in[22]; const float* f1b  = (const float*)d_in[23];
    const float* f2w  = (const float*)d_in[24]; const float* f2b  = (const float*)d_in[25];
    const float* f3w  = (const float*)d_in[26]; const float* f3b  = (const float*)d_in[27];

    const int* src = eidx;
    const int* dst = eidx + NEDGE;
    float* out = (float*)d_out;

    const float INV_N = 1.f / (float)NNODE;
    const float INV_B = 1.f / (float)BGRAPH;
    const int KBIG = 1 << 30;

    // ---- workspace layout ----
    float* ws   = (float*)d_ws;
    float* big  = ws;
    float* aux  = ws + (size_t)NNODE * 128;
    float* sb   = aux + (size_t)NNODE * 9;              // 10*1032 stats floats
    unsigned short* wtb = (unsigned short*)(sb + 10 * 1032);
    auto ST = [&](int i) { return sb + (size_t)i * 1032; };
    float* st_u1    = ST(0);
    float* st_u2rel = ST(1);
    float* st_u3    = ST(2);
    float* st_u4rel = ST(3);
    float* st_c1    = ST(4);
    float* st_c2    = ST(5);
    float* st_c3    = ST(6);
    float* st_d1    = ST(7);
    float* st_f1    = ST(8);
    float* st_f2    = ST(9);

    struct WDef { const float* w; int K; int N; };
    WDef wd[11] = {
        {ce1w, CELLD, 516}, {ce2w, 516, 256}, {ce3w, 256, 128},
        {g11w, 9, 128}, {g12w, 128, 128}, {g21w, 128, 128}, {g22w, 128, 128},
        {d1w, 128, 128}, {d2w, 128, 128}, {f1w, 256, 128}, {f2w, 128, 64}
    };
    SetupArgs sa;
    int off = 0;
    unsigned short* wt[11];
    for (int i = 0; i < 11; ++i) {
        wt[i] = wtb + off;
        sa.s[i] = TSeg{ wd[i].w, wt[i], wd[i].K, wd[i].N, off };
        off += wd[i].K * wd[i].N;
    }
    sa.tTotal = off;
    sa.tBlocks = (off + 255) / 256;
    sa.zb = sb; sa.zTotal = 10 * 1032; sa.zBlocks = (10 * 1032 + 255) / 256;
    sa.src = src; sa.dst = dst;

    int csr_off = (off + 7) & ~7;
    int* row_start = (int*)(wtb + csr_off);
    int* col_idx   = row_start + (size_t)BGRAPH * 33;
    sa.row_start = row_start; sa.col_idx = col_idx;

    float* c1    = big;
    float* c2    = c1 + (size_t)BGRAPH * 516;
    float* c3u   = c2 + (size_t)BGRAPH * 256;
    float* dbuf  = c3u + (size_t)BGRAPH * 128;
    float* d2buf = dbuf + (size_t)BGRAPH * 128;
    float* f1o   = d2buf + (size_t)BGRAPH * 128;
    float* f2o   = f1o + (size_t)BGRAPH * 128;
    float* pbuf  = aux;

    setup_all<<<sa.tBlocks + sa.zBlocks + BGRAPH / 4, 256, 0, stream>>>(sa);

    // ================= GIN branch: recompute chain ===========================
    gin_chain<1><<<BGRAPH / 4, 256, 0, stream>>>(
        drug_x, row_start, col_idx, wt[3], g11b, wt[4], g12b, wt[5], g21b, wt[6], g22b,
        st_u1, st_u2rel, st_u3, INV_N, st_u1, nullptr);
    gin_chain<2><<<BGRAPH / 4, 256, 0, stream>>>(
        drug_x, row_start, col_idx, wt[3], g11b, wt[4], g12b, wt[5], g21b, wt[6], g22b,
        st_u1, st_u2rel, st_u3, INV_N, st_u2rel, nullptr);
    gin_chain<3><<<BGRAPH / 4, 256, 0, stream>>>(
        drug_x, row_start, col_idx, wt[3], g11b, wt[4], g12b, wt[5], g21b, wt[6], g22b,
        st_u1, st_u2rel, st_u3, INV_N, st_u3, nullptr);
    gin_chain<4><<<BGRAPH / 4, 256, 0, stream>>>(
        drug_x, row_start, col_idx, wt[3], g11b, wt[4], g12b, wt[5], g21b, wt[6], g22b,
        st_u1, st_u2rel, st_u3, INV_N, st_u4rel, pbuf);

    // ================= cell branch ===========================================
    gemm_cell<128><<<dim3(BGRAPH / 64, 5), 256, 0, stream>>>(
        cell, wt[0], ce1b, c1, BGRAPH, CELLD, 516, nullptr, 0.f, 0, st_c1);
    gemm_cell<64><<<dim3(BGRAPH / 64, 4), 256, 0, stream>>>(
        c1, wt[1], ce2b, c2, BGRAPH, 516, 256, st_c1, INV_B, 1, st_c2);
    gemm_rA<8, 128><<<BGRAPH / 64, 256, 0, stream>>>(
        c2, nullptr, 256, 256, 256, KBIG, wt[2], ce3b, c3u,
        st_c2, INV_B, 1, st_c3, 1, 0);

    // ================= d branch ==============================================
    gemm_rA<4, 128><<<BGRAPH / 64, 256, 0, stream>>>(
        pbuf, nullptr, 128, 128, 128, KBIG, wt[7], d1b, dbuf,
        st_u4rel, INV_N, 3, st_d1, 1, 0);
    gemm_rA<4, 128><<<BGRAPH / 64, 256, 0, stream>>>(
        dbuf, nullptr, 128, 128, 128, KBIG, wt[8], d2b, d2buf,
        st_d1, INV_B, 1, nullptr, 0, 1);

    // ================= head ==================================================
    gemm_rA<8, 128><<<BGRAPH / 64, 256, 0, stream>>>(
        c3u, d2buf, 128, 256, 128, 128, wt[9], f1b, f1o,
        st_c3, INV_B, 1, st_f1, 1, 0);
    gemm_rA<4, 64><<<BGRAPH / 64, 256, 0, stream>>>(
        f1o, nullptr, 128, 128, 128, KBIG, wt[10], f2b, f2o,
        st_f1, INV_B, 2, st_f2, 1, 0);
    final_dot<<<BGRAPH / 256, 256, 0, stream>>>(f2o, f3w, f3b, out, st_f2, INV_B);
}

// Round 13
// 741.195 us; speedup vs baseline: 2.3500x; 1.0443x over previous
//
#include <hip/hip_runtime.h>
#include <hip/hip_bf16.h>
#include <math.h>

// Problem constants (from reference)
#define BGRAPH 8192
#define NPG 32
#define EPG 64
#define NNODE (BGRAPH * NPG)   // 262144
#define NEDGE (BGRAPH * EPG)   // 524288
#define CELLD 908
#define BN_EPS 1e-5f

typedef __attribute__((ext_vector_type(8))) short bf16x8;   // 8 bf16 = 4 VGPRs
typedef __attribute__((ext_vector_type(4))) float f32x4;
typedef __attribute__((ext_vector_type(4))) unsigned short us4;

__device__ __forceinline__ unsigned short f2bf(float f)
{
    unsigned int u = __float_as_uint(f);
    u = (u + 0x7FFFu + ((u >> 16) & 1u)) >> 16;   // RNE
    return (unsigned short)u;
}

__device__ __forceinline__ bf16x8 quant8(const float v[8])
{
    union { bf16x8 b; unsigned short u[8]; } fr;
    #pragma unroll
    for (int j = 0; j < 8; ++j) fr.u[j] = f2bf(v[j]);
    return fr.b;
}

__device__ __forceinline__ void bf2f8(bf16x8 b, float v[8])
{
    union { bf16x8 bb; unsigned short u[8]; } x; x.bb = b;
    #pragma unroll
    for (int j = 0; j < 8; ++j) v[j] = __uint_as_float((unsigned)x.u[j] << 16);
}

// in_mode: 0=raw, 1=relu((x-m)*iv), 2=elu((x-m)*iv), 3=(relu(x)-m)*iv
__device__ __forceinline__ float apply_in(float v, int mode, float mn, float iv)
{
    if (mode == 1)      { v = (v - mn) * iv; v = fmaxf(v, 0.f); }
    else if (mode == 2) { v = (v - mn) * iv; v = (v > 0.f) ? v : expm1f(v); }
    else if (mode == 3) { v = fmaxf(v, 0.f); v = (v - mn) * iv; }
    return v;
}

// ---------------------------------------------------------------------------
// Merged setup: weight transpose+bf16, stats zero, per-graph in-edge CSR.
// ---------------------------------------------------------------------------
struct TSeg { const float* w; unsigned short* wt; int K; int N; int off; };
struct SetupArgs {
    TSeg s[11]; int tTotal; int tBlocks;
    float* zb; int zTotal; int zBlocks;
    const int* src; const int* dst; int* row_start; int* col_idx;
};

__global__ void setup_all(SetupArgs a)
{
    int b = blockIdx.x;
    int tid = threadIdx.x;
    if (b < a.tBlocks) {
        int i = b * 256 + tid;
        if (i < a.tTotal) {
            int j = 0;
            while (j < 10 && i >= a.s[j + 1].off) ++j;
            int idx = i - a.s[j].off;
            int K = a.s[j].K, N = a.s[j].N;
            int n = idx / K, k = idx - n * K;
            a.s[j].wt[idx] = f2bf(a.s[j].w[(size_t)k * N + n]);
        }
        return;
    }
    b -= a.tBlocks;
    if (b < a.zBlocks) {
        int i = b * 256 + tid;
        if (i < a.zTotal) a.zb[i] = 0.f;
        return;
    }
    b -= a.zBlocks;
    // CSR build: 4 graphs per block
    __shared__ int cnt[4][32], fill[4][32], rsl[4][33];
    int gl = tid >> 6, e = tid & 63;
    int g = b * 4 + gl;
    if (e < 32) { cnt[gl][e] = 0; fill[gl][e] = 0; }
    __syncthreads();
    int s = a.src[g * EPG + e] - g * NPG;
    int d = a.dst[g * EPG + e] - g * NPG;
    atomicAdd(&cnt[gl][d], 1);
    __syncthreads();
    if (e == 0) {
        int acc = 0;
        for (int i = 0; i < 32; ++i) { rsl[gl][i] = acc; acc += cnt[gl][i]; }
        rsl[gl][32] = acc;
    }
    __syncthreads();
    int pos = rsl[gl][d] + atomicAdd(&fill[gl][d], 1);
    a.col_idx[g * EPG + pos] = s;
    if (e < 33) a.row_start[g * 33 + e] = rsl[gl][e];
}

// ---------------------------------------------------------------------------
// GIN chain by RECOMPUTE: block = 4 graphs, wave = 1 graph.
// Per stage: (1) A-frags from wave-private bf16 h tile -> registers;
// (2) barrier + cooperative W stage into LDS OVERLAYING h (one 32KB fetch
// per BLOCK, not per wave); (3) barrier + MFMA with B-frags from LDS.
// transform_store has a leading barrier (h overwrites the W overlay).
// LDS 40.5 KB -> 4 blocks/CU. Stats: wave reduce -> block reduce -> atomics.
// Chain: a = x + agg(x); u1 = a@W11+b11 [stats raw @D1]
//        u2 = relu(bn(u1))@W12+b12     [stats relu @D2]
//        h  = bn(relu(u2)); u3 = (h+agg(h))@W21+b21 [stats raw @D3]
//        u4 = relu(bn(u3))@W22+b22     [stats relu + pool @D4]
// ---------------------------------------------------------------------------
#define HBS 136   // bf16 h row stride (ushorts): 272 B, 16B-aligned

template<int DEPTH>
__launch_bounds__(256)
__global__ void gin_chain(const float* __restrict__ drug_x,
                          const int* __restrict__ row_start,
                          const int* __restrict__ col_idx,
                          const unsigned short* __restrict__ W11,   // [128][9]
                          const float* __restrict__ b11,
                          const unsigned short* __restrict__ W12, const float* __restrict__ b12,
                          const unsigned short* __restrict__ W21, const float* __restrict__ b21,
                          const unsigned short* __restrict__ W22, const float* __restrict__ b22,
                          const float* __restrict__ st1,
                          const float* __restrict__ st2,
                          const float* __restrict__ st3,
                          float invM,
                          float* __restrict__ out_stats,
                          float* __restrict__ pool_out)
{
    __shared__ __align__(16) unsigned short h[4 * 32 * HBS];    // 34816 B; W overlay
    __shared__ __align__(16) unsigned char ubuf[4096];          // w11l <-> red overlay
    __shared__ int rs[4][36];                                   // 576 B
    __shared__ int ci[4][64];                                   // 1024 B

    unsigned short* w11l = (unsigned short*)ubuf;   // [128][16], stage 1 only
    float* red = (float*)ubuf;                      // epilogue block reduce
    unsigned short* wsl = h;                        // [128][136] W overlay (34816 sh)

    int tid  = threadIdx.x;
    int wave = tid >> 6;
    int lane = tid & 63;
    int quad = lane >> 4;
    int l16  = lane & 15;
    int g0   = blockIdx.x * 4;
    unsigned short* hw = h + wave * (32 * HBS);
    float* xw = (float*)hw;          // stage-1 fp32 x tile (32x16), overlaid

    // ---- cooperative staging (single barrier) ----
    for (int i = tid; i < 128 * 16; i += 256) {
        int n = i >> 4, k = i & 15;
        w11l[i] = (k < 9) ? W11[n * 9 + k] : (unsigned short)0;
    }
    if (tid < 132) {
        int gl = tid / 33, idx = tid - gl * 33;
        rs[gl][idx] = row_start[(g0 + gl) * 33 + idx];
    }
    {
        int gl = tid >> 6, e = tid & 63;
        ci[gl][e] = col_idx[(g0 + gl) * EPG + e];
    }
    {
        const float* xg = drug_x + (size_t)(g0 + wave) * 32 * 9;
        for (int i = lane; i < 32 * 16; i += 64) {
            int rr = i >> 4, c = i & 15;
            xw[i] = (c < 9) ? xg[rr * 9 + c] : 0.f;     // wave-private region
        }
    }
    __syncthreads();

    f32x4 acc[2][8];
    #pragma unroll
    for (int i = 0; i < 2; ++i)
        #pragma unroll
        for (int j = 0; j < 8; ++j)
            acc[i][j] = (f32x4){0.f, 0.f, 0.f, 0.f};

    // ======== stage 1: u1 = (x + agg(x)) @ W11 + b11 (fp32 gather) ==========
    {
        bf16x8 af[2];
        #pragma unroll
        for (int mt = 0; mt < 2; ++mt) {
            int rowl = mt * 16 + l16;
            float v[8] = {0, 0, 0, 0, 0, 0, 0, 0};
            if (quad < 2) {
                float4 lo = *(const float4*)&xw[rowl * 16 + quad * 8];
                float4 hi = *(const float4*)&xw[rowl * 16 + quad * 8 + 4];
                v[0] = lo.x; v[1] = lo.y; v[2] = lo.z; v[3] = lo.w;
                v[4] = hi.x; v[5] = hi.y; v[6] = hi.z; v[7] = hi.w;
                int e0 = rs[wave][rowl], e1 = rs[wave][rowl + 1];
                for (int e = e0; e < e1; ++e) {
                    int sr = ci[wave][e];
                    float4 l2 = *(const float4*)&xw[sr * 16 + quad * 8];
                    float4 h2 = *(const float4*)&xw[sr * 16 + quad * 8 + 4];
                    v[0] += l2.x; v[1] += l2.y; v[2] += l2.z; v[3] += l2.w;
                    v[4] += h2.x; v[5] += h2.y; v[6] += h2.z; v[7] += h2.w;
                }
            }
            af[mt] = quant8(v);
        }
        #pragma unroll
        for (int nt = 0; nt < 8; ++nt) {
            bf16x8 b;
            if (quad < 2) b = *(const bf16x8*)(const void*)&w11l[(nt * 16 + l16) * 16 + quad * 8];
            else { float z[8] = {0,0,0,0,0,0,0,0}; b = quant8(z); }
            acc[0][nt] = __builtin_amdgcn_mfma_f32_16x16x32_bf16(af[0], b, acc[0][nt], 0, 0, 0);
            acc[1][nt] = __builtin_amdgcn_mfma_f32_16x16x32_bf16(af[1], b, acc[1][nt], 0, 0, 0);
        }
        #pragma unroll
        for (int nt = 0; nt < 8; ++nt) {
            float bv = b11[nt * 16 + l16];
            #pragma unroll
            for (int mt = 0; mt < 2; ++mt)
                #pragma unroll
                for (int r = 0; r < 4; ++r) acc[mt][nt][r] += bv;
        }
    }

    // transform acc (C-layout) -> bf16 h tile. Leading barrier: the h region
    // may currently hold the previous stage's W overlay still being read.
    auto transform_store = [&](const float* st, int mode) {
        __syncthreads();
        #pragma unroll
        for (int nt = 0; nt < 8; ++nt) {
            int col = nt * 16 + l16;
            float s = st[col], ss = st[128 + col];
            float mn = s * invM;
            float iv = rsqrtf(ss * invM - mn * mn + BN_EPS);
            #pragma unroll
            for (int mt = 0; mt < 2; ++mt)
                #pragma unroll
                for (int r = 0; r < 4; ++r) {
                    float u = acc[mt][nt][r];
                    float t = (mode == 1) ? fmaxf((u - mn) * iv, 0.f)
                                          : (fmaxf(u, 0.f) - mn) * iv;
                    hw[(mt * 16 + quad * 4 + r) * HBS + col] = f2bf(t);
                }
        }
    };
    // GEMM from bf16 h tile (K=128). Phase 1: A-frags to regs; phase 2:
    // cooperative W stage into the h overlay; phase 3: MFMA, B from LDS.
    auto gemm_h = [&](const unsigned short* Wt, const float* bias, bool gather) {
        bf16x8 af[2][4];
        #pragma unroll
        for (int mt = 0; mt < 2; ++mt) {
            int rowl = mt * 16 + l16;
            if (!gather) {
                #pragma unroll
                for (int ks = 0; ks < 4; ++ks)
                    af[mt][ks] = *(const bf16x8*)(const void*)&hw[rowl * HBS + ks * 32 + quad * 8];
            } else {
                float v[4][8];
                #pragma unroll
                for (int ks = 0; ks < 4; ++ks)
                    bf2f8(*(const bf16x8*)(const void*)&hw[rowl * HBS + ks * 32 + quad * 8], v[ks]);
                int e0 = rs[wave][rowl], e1 = rs[wave][rowl + 1];
                for (int e = e0; e < e1; ++e) {
                    int sr = ci[wave][e];
                    #pragma unroll
                    for (int ks = 0; ks < 4; ++ks) {
                        float t[8];
                        bf2f8(*(const bf16x8*)(const void*)&hw[sr * HBS + ks * 32 + quad * 8], t);
                        #pragma unroll
                        for (int j = 0; j < 8; ++j) v[ks][j] += t[j];
                    }
                }
                #pragma unroll
                for (int ks = 0; ks < 4; ++ks) af[mt][ks] = quant8(v[ks]);
            }
        }
        __syncthreads();   // all waves done reading h
        // cooperative W stage: [128][128] -> wsl[128][136]
        for (int i = tid; i < 128 * 32; i += 256) {
            int n = i >> 5, k = (i & 31) * 4;
            *(us4*)&wsl[n * 136 + k] = *(const us4*)&Wt[(size_t)n * 128 + k];
        }
        __syncthreads();
        #pragma unroll
        for (int i = 0; i < 2; ++i)
            #pragma unroll
            for (int j = 0; j < 8; ++j)
                acc[i][j] = (f32x4){0.f, 0.f, 0.f, 0.f};
        #pragma unroll
        for (int ks = 0; ks < 4; ++ks) {
            int kb = ks * 32 + quad * 8;
            #pragma unroll
            for (int nt = 0; nt < 8; ++nt) {
                bf16x8 b = *(const bf16x8*)(const void*)&wsl[(nt * 16 + l16) * 136 + kb];
                acc[0][nt] = __builtin_amdgcn_mfma_f32_16x16x32_bf16(af[0][ks], b, acc[0][nt], 0, 0, 0);
                acc[1][nt] = __builtin_amdgcn_mfma_f32_16x16x32_bf16(af[1][ks], b, acc[1][nt], 0, 0, 0);
            }
        }
        #pragma unroll
        for (int nt = 0; nt < 8; ++nt) {
            float bv = bias[nt * 16 + l16];
            #pragma unroll
            for (int mt = 0; mt < 2; ++mt)
                #pragma unroll
                for (int r = 0; r < 4; ++r) acc[mt][nt][r] += bv;
        }
    };

    if constexpr (DEPTH >= 2) { transform_store(st1, 1); gemm_h(W12, b12, false); }
    if constexpr (DEPTH >= 3) { transform_store(st2, 3); gemm_h(W21, b21, true);  }
    if constexpr (DEPTH >= 4) { transform_store(st3, 1); gemm_h(W22, b22, false); }

    // ======== stats (+pool) epilogue: wave reduce -> block reduce -> atomics =
    constexpr bool RELU_STATS = (DEPTH == 2 || DEPTH == 4);
    float ls[8], lq[8];
    #pragma unroll
    for (int nt = 0; nt < 8; ++nt) {
        int col = nt * 16 + l16;
        float s0 = 0.f, q0 = 0.f, mx = -INFINITY;
        #pragma unroll
        for (int mt = 0; mt < 2; ++mt)
            #pragma unroll
            for (int r = 0; r < 4; ++r) {
                float u = acc[mt][nt][r];
                float ru = fmaxf(u, 0.f);
                float s = RELU_STATS ? ru : u;
                s0 += s; q0 += s * s;
                if (DEPTH == 4) mx = fmaxf(mx, ru);
            }
        ls[nt] = s0; lq[nt] = q0;
        if (DEPTH == 4) {
            mx = fmaxf(mx, __shfl_xor(mx, 16));
            mx = fmaxf(mx, __shfl_xor(mx, 32));
            if (quad == 0) pool_out[(size_t)(g0 + wave) * 128 + col] = mx;
        }
    }
    __syncthreads();   // all waves done with w11l/W before red overlay
    #pragma unroll
    for (int nt = 0; nt < 8; ++nt) {
        float s = ls[nt], q = lq[nt];
        s += __shfl_xor(s, 16); q += __shfl_xor(q, 16);
        s += __shfl_xor(s, 32); q += __shfl_xor(q, 32);
        if (quad == 0) {
            int col = nt * 16 + l16;
            red[(wave * 2 + 0) * 128 + col] = s;
            red[(wave * 2 + 1) * 128 + col] = q;
        }
    }
    __syncthreads();
    if (tid < 128) {
        float s = red[0 * 128 + tid] + red[2 * 128 + tid] + red[4 * 128 + tid] + red[6 * 128 + tid];
        float q = red[1 * 128 + tid] + red[3 * 128 + tid] + red[5 * 128 + tid] + red[7 * 128 + tid];
        unsafeAtomicAdd(&out_stats[tid], s);
        unsafeAtomicAdd(&out_stats[128 + tid], q);
    }
}

// ---------------------------------------------------------------------------
// Register-A MFMA GEMM for the 8192-row layers. Tile 64 x NT, K <= KSTEPS*32.
// In-place safe.
// ---------------------------------------------------------------------------
template<int KSTEPS, int NT>
__launch_bounds__(256)
__global__ void gemm_rA(const float* __restrict__ A, const float* __restrict__ A2,
                        int lda, int K, int stats_K, int ksplit,
                        const unsigned short* __restrict__ Wt,
                        const float* __restrict__ bias, float* __restrict__ C,
                        const float* __restrict__ in_stats, float inv_sM, int in_mode,
                        float* __restrict__ out_stats, int stats_mode, int out_act)
{
    constexpr int LSTRW = KSTEPS * 32 + 8;
    constexpr int NSUB = NT / 16;
    __shared__ unsigned short Ws_l[NT * LSTRW];
    __shared__ float pm[KSTEPS * 32], pv[KSTEPS * 32];
    __shared__ float red[4][2][NT];

    int tid  = threadIdx.x;
    int wave = tid >> 6;
    int lane = tid & 63;
    int quad = lane >> 4;
    int l16  = lane & 15;
    int m0   = blockIdx.x * 64;

    const bool kvec = ((K & 3) == 0);

    for (int i = tid; i < NT * (KSTEPS * 8); i += 256) {
        int n = i / (KSTEPS * 8), g4 = i % (KSTEPS * 8);
        int k = g4 * 4;
        us4 w = (us4){0, 0, 0, 0};
        if (k < K) {
            const unsigned short* wp = Wt + (size_t)n * K + k;
            if (kvec) w = *(const us4*)wp;
            else {
                w.x = wp[0];
                if (k + 1 < K) w.y = wp[1];
                if (k + 2 < K) w.z = wp[2];
                if (k + 3 < K) w.w = wp[3];
            }
        }
        *(us4*)&Ws_l[n * LSTRW + k] = w;
    }
    if (in_mode) {
        for (int k = tid; k < KSTEPS * 32; k += 256) {
            float mn = 0.f, iv = 1.f;
            if (k < stats_K) {
                float s = in_stats[k], ss = in_stats[stats_K + k];
                mn = s * inv_sM;
                float vr = ss * inv_sM - mn * mn;
                iv = rsqrtf(vr + BN_EPS);
            }
            pm[k] = mn; pv[k] = iv;
        }
    }
    __syncthreads();

    bf16x8 afrag[KSTEPS];
    {
        int row = m0 + wave * 16 + l16;
        const float* ap = A + (size_t)row * lda;
        #pragma unroll
        for (int ks = 0; ks < KSTEPS; ++ks) {
            int kb = ks * 32 + quad * 8;
            float v[8];
            if (kvec) {
                #pragma unroll
                for (int hh = 0; hh < 2; ++hh) {
                    int k = kb + hh * 4;
                    const float* p = (k >= ksplit) ? &A2[(size_t)row * 128 + (k - 128)]
                                                   : &ap[k];
                    float4 f = *(const float4*)p;
                    v[hh * 4 + 0] = f.x; v[hh * 4 + 1] = f.y;
                    v[hh * 4 + 2] = f.z; v[hh * 4 + 3] = f.w;
                }
            } else {
                #pragma unroll
                for (int j = 0; j < 8; ++j) {
                    int k = kb + j;
                    v[j] = (k < K) ? ap[k] : 0.f;
                }
            }
            if (in_mode) {
                #pragma unroll
                for (int j = 0; j < 8; ++j)
                    v[j] = apply_in(v[j], in_mode, pm[kb + j], pv[kb + j]);
            }
            afrag[ks] = quant8(v);
        }
    }

    f32x4 acc[NSUB];
    #pragma unroll
    for (int j = 0; j < NSUB; ++j) acc[j] = (f32x4){0.f, 0.f, 0.f, 0.f};

    #pragma unroll
    for (int ks = 0; ks < KSTEPS; ++ks) {
        #pragma unroll
        for (int nt = 0; nt < NSUB; ++nt) {
            bf16x8 b = *(const bf16x8*)(const void*)&Ws_l[(nt * 16 + l16) * LSTRW + ks * 32 + quad * 8];
            acc[nt] = __builtin_amdgcn_mfma_f32_16x16x32_bf16(afrag[ks], b, acc[nt], 0, 0, 0);
        }
    }

    float ls[NSUB], lq[NSUB];
    #pragma unroll
    for (int nt = 0; nt < NSUB; ++nt) { ls[nt] = 0.f; lq[nt] = 0.f; }

    #pragma unroll
    for (int nt = 0; nt < NSUB; ++nt) {
        int col = nt * 16 + l16;
        float bv = bias[col];
        int rbase = m0 + wave * 16 + quad * 4;
        #pragma unroll
        for (int r = 0; r < 4; ++r) {
            float u = acc[nt][r] + bv;
            if (C) {
                float wv = out_act ? fmaxf(u, 0.f) : u;
                C[(size_t)(rbase + r) * NT + col] = wv;
            }
            if (stats_mode) {
                float s = (stats_mode == 2) ? fmaxf(u, 0.f) : u;
                ls[nt] += s; lq[nt] += s * s;
            }
        }
    }

    if (stats_mode) {
        #pragma unroll
        for (int nt = 0; nt < NSUB; ++nt) {
            float s = ls[nt], q = lq[nt];
            s += __shfl_xor(s, 16); q += __shfl_xor(q, 16);
            s += __shfl_xor(s, 32); q += __shfl_xor(q, 32);
            if (quad == 0) { red[wave][0][nt * 16 + l16] = s; red[wave][1][nt * 16 + l16] = q; }
        }
        __syncthreads();
        if (tid < NT) {
            float s = red[0][0][tid] + red[1][0][tid] + red[2][0][tid] + red[3][0][tid];
            float q = red[0][1][tid] + red[1][1][tid] + red[2][1][tid] + red[3][1][tid];
            unsafeAtomicAdd(&out_stats[tid], s);
            unsafeAtomicAdd(&out_stats[NT + tid], q);
        }
    }
}

// ---------------------------------------------------------------------------
// Cell-branch GEMM (large K): tile 64 x NT, 4 waves x 16 rows, K-chunk 64.
// ---------------------------------------------------------------------------
template<int NT>
__launch_bounds__(256)
__global__ void gemm_cell(const float* __restrict__ A, const unsigned short* __restrict__ Wt,
                          const float* __restrict__ bias, float* __restrict__ C,
                          int M, int K, int N,
                          const float* __restrict__ in_stats, float inv_sM, int in_mode,
                          float* __restrict__ out_stats)
{
    constexpr int NSUB = NT / 16;
    __shared__ unsigned short As_l[64 * 72];
    __shared__ unsigned short Ws_l[NT * 72];
    __shared__ float pm[916], pv[916];
    __shared__ float red[4][2][NT];

    int tid = threadIdx.x;
    int wave = tid >> 6;
    int lane = tid & 63;
    int quad = lane >> 4;
    int l16 = lane & 15;
    int m0 = blockIdx.x * 64, n0 = blockIdx.y * NT;

    if (in_mode) {
        for (int k = tid; k < K; k += 256) {
            float s = in_stats[k], ss = in_stats[K + k];
            float mn = s * inv_sM;
            float vr = ss * inv_sM - mn * mn;
            pm[k] = mn; pv[k] = rsqrtf(vr + BN_EPS);
        }
        __syncthreads();
    }

    f32x4 acc[NSUB];
    #pragma unroll
    for (int j = 0; j < NSUB; ++j) acc[j] = (f32x4){0.f, 0.f, 0.f, 0.f};

    for (int k0 = 0; k0 < K; k0 += 64) {
        for (int i = tid; i < 64 * 16; i += 256) {
            int row = i >> 4, f4 = i & 15;
            int k = k0 + f4 * 4;
            us4 w4 = (us4){0, 0, 0, 0};
            if (k < K) {
                float4 f = *(const float4*)&A[(size_t)(m0 + row) * K + k];
                if (in_mode) {
                    f.x = apply_in(f.x, in_mode, pm[k], pv[k]);
                    f.y = apply_in(f.y, in_mode, pm[k + 1], pv[k + 1]);
                    f.z = apply_in(f.z, in_mode, pm[k + 2], pv[k + 2]);
                    f.w = apply_in(f.w, in_mode, pm[k + 3], pv[k + 3]);
                }
                w4 = (us4){ f2bf(f.x), f2bf(f.y), f2bf(f.z), f2bf(f.w) };
            }
            *(us4*)&As_l[row * 72 + f4 * 4] = w4;
        }
        for (int i = tid; i < NT * 16; i += 256) {
            int nn = i >> 4, kt = i & 15;
            int k = k0 + kt * 4;
            int gn = n0 + nn;
            us4 w4 = (us4){0, 0, 0, 0};
            if (gn < N && k < K) w4 = *(const us4*)&Wt[(size_t)gn * K + k];
            *(us4*)&Ws_l[nn * 72 + kt * 4] = w4;
        }
        __syncthreads();
        int rowb = wave * 16;
        #pragma unroll
        for (int ks = 0; ks < 2; ++ks) {
            bf16x8 a = *(const bf16x8*)(const void*)&As_l[(rowb + l16) * 72 + ks * 32 + quad * 8];
            #pragma unroll
            for (int nt = 0; nt < NSUB; ++nt) {
                bf16x8 b = *(const bf16x8*)(const void*)&Ws_l[(nt * 16 + l16) * 72 + ks * 32 + quad * 8];
                acc[nt] = __builtin_amdgcn_mfma_f32_16x16x32_bf16(a, b, acc[nt], 0, 0, 0);
            }
        }
        __syncthreads();
    }

    float ls[NSUB], lq[NSUB];
    #pragma unroll
    for (int nt = 0; nt < NSUB; ++nt) { ls[nt] = 0.f; lq[nt] = 0.f; }

    #pragma unroll
    for (int nt = 0; nt < NSUB; ++nt) {
        int col = n0 + nt * 16 + l16;
        if (col < N) {
            float bv = bias[col];
            int rbase = m0 + wave * 16 + quad * 4;
            #pragma unroll
            for (int r = 0; r < 4; ++r) {
                float u = acc[nt][r] + bv;
                C[(size_t)(rbase + r) * N + col] = u;
                ls[nt] += u; lq[nt] += u * u;
            }
        }
    }

    #pragma unroll
    for (int nt = 0; nt < NSUB; ++nt) {
        float s = ls[nt], q = lq[nt];
        s += __shfl_xor(s, 16); q += __shfl_xor(q, 16);
        s += __shfl_xor(s, 32); q += __shfl_xor(q, 32);
        if (quad == 0) { red[wave][0][nt * 16 + l16] = s; red[wave][1][nt * 16 + l16] = q; }
    }
    __syncthreads();
    if (tid < NT) {
        int col = n0 + tid;
        if (col < N) {
            float s = red[0][0][tid] + red[1][0][tid] + red[2][0][tid] + red[3][0][tid];
            float q = red[0][1][tid] + red[1][1][tid] + red[2][1][tid] + red[3][1][tid];
            unsafeAtomicAdd(&out_stats[col], s);
            unsafeAtomicAdd(&out_stats[N + col], q);
        }
    }
}

// ---------------------------------------------------------------------------
// Final: y[i] = elu(bn(u[i,:])) . w + b   (K = 64)
// ---------------------------------------------------------------------------
__global__ void final_dot(const float* __restrict__ u, const float* __restrict__ w,
                          const float* __restrict__ b, float* __restrict__ y,
                          const float* __restrict__ stats, float inv_sM)
{
    __shared__ float pmv[64], piv[64], sw[64];
    int tid = threadIdx.x;
    if (tid < 64) {
        float s = stats[tid], ss = stats[64 + tid];
        float mn = s * inv_sM;
        float vr = ss * inv_sM - mn * mn;
        pmv[tid] = mn;
        piv[tid] = rsqrtf(vr + BN_EPS);
        sw[tid] = w[tid];
    }
    __syncthreads();
    int i = blockIdx.x * blockDim.x + tid;
    if (i >= BGRAPH) return;
    float acc = 0.f;
    #pragma unroll
    for (int k = 0; k < 64; ++k) {
        float v = (u[(size_t)i * 64 + k] - pmv[k]) * piv[k];
        v = (v > 0.f) ? v : expm1f(v);
        acc += v * sw[k];
    }
    y[i] = acc + b[0];
}

// ---------------------------------------------------------------------------
// Host driver. 12 launches.
// ---------------------------------------------------------------------------
extern "C" void kernel_launch(void* const* d_in, const int* in_sizes, int n_in,
                              void* d_out, int out_size, void* d_ws, size_t ws_size,
                              hipStream_t stream)
{
    const float* cell   = (const float*)d_in[0];
    const float* drug_x = (const float*)d_in[1];
    const int*   eidx   = (const int*)d_in[2];
    const float* ce1w = (const float*)d_in[4];  const float* ce1b = (const float*)d_in[5];
    const float* ce2w = (const float*)d_in[6];  const float* ce2b = (const float*)d_in[7];
    const float* ce3w = (const float*)d_in[8];  const float* ce3b = (const float*)d_in[9];
    const float* g11w = (const float*)d_in[10]; const float* g11b = (const float*)d_in[11];
    const float* g12w = (const float*)d_in[12]; const float* g12b = (const float*)d_in[13];
    const float* g21w = (const float*)d_in[14]; const float* g21b = (const float*)d_in[15];
    const float* g22w = (const float*)d_in[16]; const float* g22b = (const float*)d_in[17];
    const float* d1w  = (const float*)d_in[18]; const float* d1b  = (const float*)d_in[19];
    const float* d2w  = (const float*)d_in[20]; const float* d2b  = (const float*)d_in[21];
    const float* f1w  = (const float*)d_in[22]; const float* f1b  = (const float*)d_in[23];
    const float* f2w  = (const float*)d_in[24]; const float* f2b  = (const float*)d_in[25];
    const float* f3w  = (const float*)d_in[26]; const float* f3b  = (const float*)d_in[27];

    const int* src = eidx;
    const int* dst = eidx + NEDGE;
    float* out = (float*)d_out;

    const float INV_N = 1.f / (float)NNODE;
    const float INV_B = 1.f / (float)BGRAPH;
    const int KBIG = 1 << 30;

    // ---- workspace layout ----
    float* ws   = (float*)d_ws;
    float* big  = ws;
    float* aux  = ws + (size_t)NNODE * 128;
    float* sb   = aux + (size_t)NNODE * 9;              // 10*1032 stats floats
    unsigned short* wtb = (unsigned short*)(sb + 10 * 1032);
    auto ST = [&](int i) { return sb + (size_t)i * 1032; };
    float* st_u1    = ST(0);
    float* st_u2rel = ST(1);
    float* st_u3    = ST(2);
    float* st_u4rel = ST(3);
    float* st_c1    = ST(4);
    float* st_c2    = ST(5);
    float* st_c3    = ST(6);
    float* st_d1    = ST(7);
    float* st_f1    = ST(8);
    float* st_f2    = ST(9);

    struct WDef { const float* w; int K; int N; };
    WDef wd[11] = {
        {ce1w, CELLD, 516}, {ce2w, 516, 256}, {ce3w, 256, 128},
        {g11w, 9, 128}, {g12w, 128, 128}, {g21w, 128, 128}, {g22w, 128, 128},
        {d1w, 128, 128}, {d2w, 128, 128}, {f1w, 256, 128}, {f2w, 128, 64}
    };
    SetupArgs sa;
    int off = 0;
    unsigned short* wt[11];
    for (int i = 0; i < 11; ++i) {
        wt[i] = wtb + off;
        sa.s[i] = TSeg{ wd[i].w, wt[i], wd[i].K, wd[i].N, off };
        off += wd[i].K * wd[i].N;
    }
    sa.tTotal = off;
    sa.tBlocks = (off + 255) / 256;
    sa.zb = sb; sa.zTotal = 10 * 1032; sa.zBlocks = (10 * 1032 + 255) / 256;
    sa.src = src; sa.dst = dst;

    int csr_off = (off + 7) & ~7;
    int* row_start = (int*)(wtb + csr_off);
    int* col_idx   = row_start + (size_t)BGRAPH * 33;
    sa.row_start = row_start; sa.col_idx = col_idx;

    float* c1    = big;
    float* c2    = c1 + (size_t)BGRAPH * 516;
    float* c3u   = c2 + (size_t)BGRAPH * 256;
    float* dbuf  = c3u + (size_t)BGRAPH * 128;
    float* d2buf = dbuf + (size_t)BGRAPH * 128;
    float* f1o   = d2buf + (size_t)BGRAPH * 128;
    float* f2o   = f1o + (size_t)BGRAPH * 128;
    float* pbuf  = aux;

    setup_all<<<sa.tBlocks + sa.zBlocks + BGRAPH / 4, 256, 0, stream>>>(sa);

    // ================= GIN branch: recompute chain ===========================
    gin_chain<1><<<BGRAPH / 4, 256, 0, stream>>>(
        drug_x, row_start, col_idx, wt[3], g11b, wt[4], g12b, wt[5], g21b, wt[6], g22b,
        st_u1, st_u2rel, st_u3, INV_N, st_u1, nullptr);
    gin_chain<2><<<BGRAPH / 4, 256, 0, stream>>>(
        drug_x, row_start, col_idx, wt[3], g11b, wt[4], g12b, wt[5], g21b, wt[6], g22b,
        st_u1, st_u2rel, st_u3, INV_N, st_u2rel, nullptr);
    gin_chain<3><<<BGRAPH / 4, 256, 0, stream>>>(
        drug_x, row_start, col_idx, wt[3], g11b, wt[4], g12b, wt[5], g21b, wt[6], g22b,
        st_u1, st_u2rel, st_u3, INV_N, st_u3, nullptr);
    gin_chain<4><<<BGRAPH / 4, 256, 0, stream>>>(
        drug_x, row_start, col_idx, wt[3], g11b, wt[4], g12b, wt[5], g21b, wt[6], g22b,
        st_u1, st_u2rel, st_u3, INV_N, st_u4rel, pbuf);

    // ================= cell branch ===========================================
    gemm_cell<128><<<dim3(BGRAPH / 64, 5), 256, 0, stream>>>(
        cell, wt[0], ce1b, c1, BGRAPH, CELLD, 516, nullptr, 0.f, 0, st_c1);
    gemm_cell<64><<<dim3(BGRAPH / 64, 4), 256, 0, stream>>>(
        c1, wt[1], ce2b, c2, BGRAPH, 516, 256, st_c1, INV_B, 1, st_c2);
    gemm_rA<8, 128><<<BGRAPH / 64, 256, 0, stream>>>(
        c2, nullptr, 256, 256, 256, KBIG, wt[2], ce3b, c3u,
        st_c2, INV_B, 1, st_c3, 1, 0);

    // ================= d branch ==============================================
    gemm_rA<4, 128><<<BGRAPH / 64, 256, 0, stream>>>(
        pbuf, nullptr, 128, 128, 128, KBIG, wt[7], d1b, dbuf,
        st_u4rel, INV_N, 3, st_d1, 1, 0);
    gemm_rA<4, 128><<<BGRAPH / 64, 256, 0, stream>>>(
        dbuf, nullptr, 128, 128, 128, KBIG, wt[8], d2b, d2buf,
        st_d1, INV_B, 1, nullptr, 0, 1);

    // ================= head ==================================================
    gemm_rA<8, 128><<<BGRAPH / 64, 256, 0, stream>>>(
        c3u, d2buf, 128, 256, 128, 128, wt[9], f1b, f1o,
        st_c3, INV_B, 1, st_f1, 1, 0);
    gemm_rA<4, 64><<<BGRAPH / 64, 256, 0, stream>>>(
        f1o, nullptr, 128, 128, 128, KBIG, wt[10], f2b, f2o,
        st_f1, INV_B, 2, st_f2, 1, 0);
    final_dot<<<BGRAPH / 256, 256, 0, stream>>>(f2o, f3w, f3b, out, st_f2, INV_B);
}